// Round 1
// baseline (1716.470 us; speedup 1.0000x reference)
//
#include <hip/hip_runtime.h>
#include <hip/hip_bf16.h>

// Nystrom attention TransLayer, MI355X. Round 1: correctness-first fp32.
// B=1, N=16384, DIM=512, H=8, DH=64, M=256 landmarks, 6 pinv iters, conv k=33.

#define FMA16(ACC, AV, BV) do { \
  ACC[0][0] += AV.x*BV.x; ACC[0][1] += AV.x*BV.y; ACC[0][2] += AV.x*BV.z; ACC[0][3] += AV.x*BV.w; \
  ACC[1][0] += AV.y*BV.x; ACC[1][1] += AV.y*BV.y; ACC[1][2] += AV.y*BV.z; ACC[1][3] += AV.y*BV.w; \
  ACC[2][0] += AV.z*BV.x; ACC[2][1] += AV.z*BV.y; ACC[2][2] += AV.z*BV.z; ACC[2][3] += AV.z*BV.w; \
  ACC[3][0] += AV.w*BV.x; ACC[3][1] += AV.w*BV.y; ACC[3][2] += AV.w*BV.z; ACC[3][3] += AV.w*BV.w; \
} while (0)

// ---------------- LayerNorm: x[16384,512] -> h ----------------
__global__ __launch_bounds__(128) void k_ln(const float* __restrict__ x,
    const float* __restrict__ w, const float* __restrict__ b, float* __restrict__ h) {
  const int row = blockIdx.x;
  const int t = threadIdx.x;
  const float4 xv = ((const float4*)(x + (size_t)row * 512))[t];
  float s  = xv.x + xv.y + xv.z + xv.w;
  float sq = xv.x*xv.x + xv.y*xv.y + xv.z*xv.z + xv.w*xv.w;
  #pragma unroll
  for (int o = 32; o > 0; o >>= 1) {
    s  += __shfl_down(s, o, 64);
    sq += __shfl_down(sq, o, 64);
  }
  __shared__ float ls[2], lq[2];
  if ((t & 63) == 0) { ls[t >> 6] = s; lq[t >> 6] = sq; }
  __syncthreads();
  s = ls[0] + ls[1]; sq = lq[0] + lq[1];
  const float mean = s * (1.0f / 512.0f);
  const float var  = sq * (1.0f / 512.0f) - mean * mean;
  const float rstd = rsqrtf(var + 1e-5f);
  const float4 wv = ((const float4*)w)[t];
  const float4 bv = ((const float4*)b)[t];
  float4 hv;
  hv.x = (xv.x - mean) * rstd * wv.x + bv.x;
  hv.y = (xv.y - mean) * rstd * wv.y + bv.y;
  hv.z = (xv.z - mean) * rstd * wv.z + bv.z;
  hv.w = (xv.w - mean) * rstd * wv.w + bv.w;
  ((float4*)(h + (size_t)row * 512))[t] = hv;
}

// ---------------- QKV: C[16384,1536] = h @ w_qkv^T, scatter to q,k,v ----------------
__global__ __launch_bounds__(256) void k_qkv(const float* __restrict__ A,
    const float* __restrict__ B, float* __restrict__ q, float* __restrict__ kk,
    float* __restrict__ vv) {
  __shared__ float As[16][68];
  __shared__ float Bs[16][68];
  const int t = threadIdx.x, tx = t & 15, ty = t >> 4;
  const int bn = blockIdx.x, bm = blockIdx.y;
  const int lr = t >> 2, lk = (t & 3) << 2;
  const float* Ap = A + (size_t)(bm * 64 + lr) * 512 + lk;
  const float* Bp = B + (size_t)(bn * 64 + lr) * 512 + lk;
  float acc[4][4] = {{0.f}};
  for (int k0 = 0; k0 < 512; k0 += 16) {
    const float4 a4 = *(const float4*)(Ap + k0);
    const float4 b4 = *(const float4*)(Bp + k0);
    __syncthreads();
    As[lk+0][lr] = a4.x; As[lk+1][lr] = a4.y; As[lk+2][lr] = a4.z; As[lk+3][lr] = a4.w;
    Bs[lk+0][lr] = b4.x; Bs[lk+1][lr] = b4.y; Bs[lk+2][lr] = b4.z; Bs[lk+3][lr] = b4.w;
    __syncthreads();
    #pragma unroll
    for (int kq = 0; kq < 16; ++kq) {
      const float4 av = *(const float4*)&As[kq][ty << 2];
      const float4 bv = *(const float4*)&Bs[kq][tx << 2];
      FMA16(acc, av, bv);
    }
  }
  #pragma unroll
  for (int ii = 0; ii < 4; ++ii)
    #pragma unroll
    for (int jj = 0; jj < 4; ++jj) {
      const int i = bm * 64 + (ty << 2) + ii;
      const int j = bn * 64 + (tx << 2) + jj;
      const int part = j >> 9, rem = j & 511;
      const int hd = rem >> 6, dd = rem & 63;
      const size_t idx = ((size_t)hd * 16384 + i) * 64 + dd;
      const float val = acc[ii][jj];
      if (part == 0)      q[idx]  = val * 0.125f;
      else if (part == 1) kk[idx] = val;
      else                vv[idx] = val;
    }
}

// ---------------- landmarks: mean over groups of 64 tokens ----------------
__global__ __launch_bounds__(64) void k_landmark(const float* __restrict__ q,
    const float* __restrict__ k, float* __restrict__ ql, float* __restrict__ kl) {
  const int d = threadIdx.x;
  const int m = blockIdx.x, h = blockIdx.y;
  const float* src = blockIdx.z == 0 ? q : k;
  float* dst       = blockIdx.z == 0 ? ql : kl;
  const float* p = src + ((size_t)h * 16384 + m * 64) * 64 + d;
  float s = 0.f;
  #pragma unroll 8
  for (int t2 = 0; t2 < 64; ++t2) s += p[(size_t)t2 * 64];
  dst[((size_t)h * 256 + m) * 64 + d] = s * (1.0f / 64.0f);
}

// ---------------- attn2 = softmax(q_l @ k_l^T) rows ----------------
__global__ __launch_bounds__(256) void k_attn2(const float* __restrict__ ql,
    const float* __restrict__ kl, float* __restrict__ a2) {
  const int i = blockIdx.x, h = blockIdx.y, j = threadIdx.x;
  __shared__ float qrow[64];
  __shared__ float wred[4];
  __shared__ float wsum[4];
  if (j < 64) qrow[j] = ql[((size_t)h * 256 + i) * 64 + j];
  __syncthreads();
  const float* kr = kl + ((size_t)h * 256 + j) * 64;
  float s = 0.f;
  #pragma unroll 8
  for (int d = 0; d < 64; ++d) s += qrow[d] * kr[d];
  float mx = s;
  #pragma unroll
  for (int o2 = 32; o2 > 0; o2 >>= 1) mx = fmaxf(mx, __shfl_xor(mx, o2, 64));
  if ((j & 63) == 0) wred[j >> 6] = mx;
  __syncthreads();
  mx = fmaxf(fmaxf(wred[0], wred[1]), fmaxf(wred[2], wred[3]));
  const float e = __expf(s - mx);
  float sm = e;
  #pragma unroll
  for (int o2 = 32; o2 > 0; o2 >>= 1) sm += __shfl_xor(sm, o2, 64);
  if ((j & 63) == 0) wsum[j >> 6] = sm;
  __syncthreads();
  sm = wsum[0] + wsum[1] + wsum[2] + wsum[3];
  a2[((size_t)h * 256 + i) * 256 + j] = e / sm;
}

// ---------------- max column-sum per head (col-sum of abs(a2); a2 >= 0) ----------------
__global__ __launch_bounds__(256) void k_colsum(const float* __restrict__ a2,
    float* __restrict__ cm) {
  const int h = blockIdx.x, j = threadIdx.x;
  const float* p = a2 + (size_t)h * 65536 + j;
  float s = 0.f;
  for (int i = 0; i < 256; ++i) s += p[(size_t)i * 256];
  float mx = s;
  #pragma unroll
  for (int o2 = 32; o2 > 0; o2 >>= 1) mx = fmaxf(mx, __shfl_xor(mx, o2, 64));
  __shared__ float wred[4];
  if ((j & 63) == 0) wred[j >> 6] = mx;
  __syncthreads();
  if (j == 0) cm[h] = fmaxf(fmaxf(wred[0], wred[1]), fmaxf(wred[2], wred[3]));
}

// ---------------- z0 = a2^T / (max colsum)  (row sums are exactly 1) ----------------
__global__ __launch_bounds__(256) void k_z0(const float* __restrict__ a2,
    const float* __restrict__ cm, float* __restrict__ z) {
  const int i = blockIdx.x, h = blockIdx.y, j = threadIdx.x;
  float g = cm[0];
  #pragma unroll
  for (int c = 1; c < 8; ++c) g = fmaxf(g, cm[c]);
  z[((size_t)h * 256 + i) * 256 + j] = a2[((size_t)h * 256 + j) * 256 + i] / g;
}

// ---------------- batched M=256,K=256 GEMM: C = alpha * A @ (diag? sI-B : B), opt B-row scale 1/rs[k] ----------------
__global__ __launch_bounds__(256) void k_gemm256(const float* __restrict__ A,
    const float* __restrict__ B, float* __restrict__ C,
    int lda, int ldb, int ldc,
    unsigned long long sA, unsigned long long sB, unsigned long long sC,
    float alpha, float sdiag, int use_diag,
    const float* __restrict__ rs, unsigned long long sRS) {
  A += (size_t)blockIdx.z * sA;
  B += (size_t)blockIdx.z * sB;
  C += (size_t)blockIdx.z * sC;
  if (rs) rs += (size_t)blockIdx.z * sRS;
  __shared__ float As[16][68];
  __shared__ float Bs[16][68];
  const int t = threadIdx.x, tx = t & 15, ty = t >> 4;
  const int bn = blockIdx.x, bm = blockIdx.y;
  const int lr = t >> 2, lk = (t & 3) << 2;
  const int bkr = t >> 4, bnc = (t & 15) << 2;
  float acc[4][4] = {{0.f}};
  for (int k0 = 0; k0 < 256; k0 += 16) {
    float4 a4 = *(const float4*)(A + (size_t)(bm * 64 + lr) * lda + k0 + lk);
    float4 b4 = *(const float4*)(B + (size_t)(k0 + bkr) * ldb + bn * 64 + bnc);
    if (use_diag) {
      const int kg = k0 + bkr, ngb = bn * 64 + bnc;
      b4.x = (kg == ngb + 0 ? sdiag : 0.f) - b4.x;
      b4.y = (kg == ngb + 1 ? sdiag : 0.f) - b4.y;
      b4.z = (kg == ngb + 2 ? sdiag : 0.f) - b4.z;
      b4.w = (kg == ngb + 3 ? sdiag : 0.f) - b4.w;
    }
    if (rs) {
      const float rv = 1.0f / rs[k0 + bkr];
      b4.x *= rv; b4.y *= rv; b4.z *= rv; b4.w *= rv;
    }
    __syncthreads();
    As[lk+0][lr] = a4.x; As[lk+1][lr] = a4.y; As[lk+2][lr] = a4.z; As[lk+3][lr] = a4.w;
    *(float4*)&Bs[bkr][bnc] = b4;
    __syncthreads();
    #pragma unroll
    for (int kq = 0; kq < 16; ++kq) {
      const float4 av = *(const float4*)&As[kq][ty << 2];
      const float4 bv = *(const float4*)&Bs[kq][tx << 2];
      FMA16(acc, av, bv);
    }
  }
  #pragma unroll
  for (int ii = 0; ii < 4; ++ii)
    #pragma unroll
    for (int jj = 0; jj < 4; ++jj)
      C[(size_t)(bm * 64 + (ty << 2) + ii) * ldc + bn * 64 + (tx << 2) + jj] =
          alpha * acc[ii][jj];
}

// ---------------- fused attn3@v: Wr[h,m,d] += sum_n exp(q_l.k) v ; lsum[h,m] += sum exp ----------------
__global__ __launch_bounds__(256) void k_w3(const float* __restrict__ ql,
    const float* __restrict__ kg, const float* __restrict__ vg,
    float* __restrict__ Wr, float* __restrict__ lsum) {
  __shared__ float QLs[64][64];  // [d][m]
  __shared__ float Ks [64][64];  // [d][n]
  __shared__ float Vs [64][64];  // [n][d]
  __shared__ float Ps [64][64];  // [n][m]
  const int t = threadIdx.x, tx = t & 15, ty = t >> 4;
  const int kc = blockIdx.x, mt = blockIdx.y, h = blockIdx.z;
  {
    const int mr = t >> 2, dq = (t & 3) << 2;
    const float* p = ql + ((size_t)h * 256 + mt * 64 + mr) * 64;
    #pragma unroll
    for (int seg = 0; seg < 4; ++seg) {
      const float4 v4 = *(const float4*)(p + seg * 16 + dq);
      QLs[seg*16 + dq + 0][mr] = v4.x;
      QLs[seg*16 + dq + 1][mr] = v4.y;
      QLs[seg*16 + dq + 2][mr] = v4.z;
      QLs[seg*16 + dq + 3][mr] = v4.w;
    }
  }
  float wacc[4][4] = {{0.f}};
  float lacc[4] = {0.f, 0.f, 0.f, 0.f};
  for (int ss = 0; ss < 16; ++ss) {
    const int n0 = kc * 1024 + ss * 64;
    __syncthreads();
    {
      const int nr = t >> 2, dq = (t & 3) << 2;
      const float* p = kg + ((size_t)h * 16384 + n0 + nr) * 64;
      #pragma unroll
      for (int seg = 0; seg < 4; ++seg) {
        const float4 v4 = *(const float4*)(p + seg * 16 + dq);
        Ks[seg*16 + dq + 0][nr] = v4.x;
        Ks[seg*16 + dq + 1][nr] = v4.y;
        Ks[seg*16 + dq + 2][nr] = v4.z;
        Ks[seg*16 + dq + 3][nr] = v4.w;
      }
      const int vr = t >> 4, vc = (t & 15) << 2;
      #pragma unroll
      for (int seg = 0; seg < 4; ++seg) {
        const float4 v4 = *(const float4*)(vg + ((size_t)h * 16384 + n0 + vr + seg * 16) * 64 + vc);
        *(float4*)&Vs[vr + seg * 16][vc] = v4;
      }
    }
    __syncthreads();
    float s[4][4] = {{0.f}};
    #pragma unroll
    for (int d = 0; d < 64; ++d) {
      const float4 av = *(const float4*)&QLs[d][ty << 2];
      const float4 bv = *(const float4*)&Ks[d][tx << 2];
      FMA16(s, av, bv);
    }
    #pragma unroll
    for (int ii = 0; ii < 4; ++ii)
      #pragma unroll
      for (int jj = 0; jj < 4; ++jj)
        Ps[(tx << 2) + jj][(ty << 2) + ii] = __expf(s[ii][jj]);
    __syncthreads();
    #pragma unroll
    for (int n = 0; n < 64; ++n) {
      const float4 av = *(const float4*)&Ps[n][ty << 2];
      const float4 bv = *(const float4*)&Vs[n][tx << 2];
      FMA16(wacc, av, bv);
      lacc[0] += av.x; lacc[1] += av.y; lacc[2] += av.z; lacc[3] += av.w;
    }
  }
  #pragma unroll
  for (int ii = 0; ii < 4; ++ii) {
    #pragma unroll
    for (int jj = 0; jj < 4; ++jj)
      atomicAdd(&Wr[((size_t)h * 256 + mt * 64 + (ty << 2) + ii) * 64 + (tx << 2) + jj],
                wacc[ii][jj]);
    if (tx == 0)
      atomicAdd(&lsum[(size_t)h * 256 + mt * 64 + (ty << 2) + ii], lacc[ii]);
  }
}

// ---------------- fused attn1 @ D: o[n, h*64+d] = softmax_m(q.k_l) @ D ----------------
__global__ __launch_bounds__(256) void k_attn1(const float* __restrict__ qg,
    const float* __restrict__ kl, const float* __restrict__ Dg, float* __restrict__ o) {
  __shared__ float Qs[64][64];            // [d][tok]
  __shared__ float Ks[64][64];            // [d][m]
  __shared__ __hip_bfloat16 Ps[256][64];  // [m][tok]
  const int t = threadIdx.x, tx = t & 15, ty = t >> 4;
  const int bt = blockIdx.x, h = blockIdx.y;
  const int n0 = bt * 64;
  {
    const int r = t >> 2, dq = (t & 3) << 2;
    const float* p = qg + ((size_t)h * 16384 + n0 + r) * 64;
    #pragma unroll
    for (int seg = 0; seg < 4; ++seg) {
      const float4 v4 = *(const float4*)(p + seg * 16 + dq);
      Qs[seg*16 + dq + 0][r] = v4.x;
      Qs[seg*16 + dq + 1][r] = v4.y;
      Qs[seg*16 + dq + 2][r] = v4.z;
      Qs[seg*16 + dq + 3][r] = v4.w;
    }
  }
  float sc[4][16];
  for (int sub = 0; sub < 4; ++sub) {
    __syncthreads();
    {
      const int r = t >> 2, dq = (t & 3) << 2;
      const float* p = kl + ((size_t)h * 256 + sub * 64 + r) * 64;
      #pragma unroll
      for (int seg = 0; seg < 4; ++seg) {
        const float4 v4 = *(const float4*)(p + seg * 16 + dq);
        Ks[seg*16 + dq + 0][r] = v4.x;
        Ks[seg*16 + dq + 1][r] = v4.y;
        Ks[seg*16 + dq + 2][r] = v4.z;
        Ks[seg*16 + dq + 3][r] = v4.w;
      }
    }
    __syncthreads();
    float s[4][4] = {{0.f}};
    #pragma unroll
    for (int d = 0; d < 64; ++d) {
      const float4 av = *(const float4*)&Qs[d][ty << 2];
      const float4 bv = *(const float4*)&Ks[d][tx << 2];
      FMA16(s, av, bv);
    }
    #pragma unroll
    for (int ii = 0; ii < 4; ++ii)
      #pragma unroll
      for (int jj = 0; jj < 4; ++jj)
        sc[ii][sub * 4 + jj] = s[ii][jj];
  }
  // softmax over 256 m (16 local x 16 tx lanes)
  #pragma unroll
  for (int ii = 0; ii < 4; ++ii) {
    float mx = sc[ii][0];
    #pragma unroll
    for (int c = 1; c < 16; ++c) mx = fmaxf(mx, sc[ii][c]);
    #pragma unroll
    for (int msk = 1; msk < 16; msk <<= 1) mx = fmaxf(mx, __shfl_xor(mx, msk, 64));
    float sm = 0.f;
    #pragma unroll
    for (int c = 0; c < 16; ++c) { sc[ii][c] = __expf(sc[ii][c] - mx); sm += sc[ii][c]; }
    #pragma unroll
    for (int msk = 1; msk < 16; msk <<= 1) sm += __shfl_xor(sm, msk, 64);
    const float inv = 1.0f / sm;
    #pragma unroll
    for (int c = 0; c < 16; ++c) sc[ii][c] *= inv;
  }
  #pragma unroll
  for (int sub = 0; sub < 4; ++sub)
    #pragma unroll
    for (int jj = 0; jj < 4; ++jj)
      #pragma unroll
      for (int ii = 0; ii < 4; ++ii)
        Ps[sub * 64 + (tx << 2) + jj][(ty << 2) + ii] =
            __float2bfloat16(sc[ii][sub * 4 + jj]);
  __syncthreads();
  float oc[4][4] = {{0.f}};
  const float* Dh = Dg + (size_t)h * 256 * 64;
  #pragma unroll 4
  for (int m = 0; m < 256; ++m) {
    const unsigned* pp = (const unsigned*)&Ps[m][ty << 2];
    const unsigned u0 = pp[0], u1 = pp[1];
    float4 av;
    av.x = __uint_as_float(u0 << 16);
    av.y = __uint_as_float(u0 & 0xffff0000u);
    av.z = __uint_as_float(u1 << 16);
    av.w = __uint_as_float(u1 & 0xffff0000u);
    const float4 bv = *(const float4*)(Dh + m * 64 + (tx << 2));
    FMA16(oc, av, bv);
  }
  #pragma unroll
  for (int ii = 0; ii < 4; ++ii)
    #pragma unroll
    for (int jj = 0; jj < 4; ++jj)
      o[(size_t)(n0 + (ty << 2) + ii) * 512 + h * 64 + (tx << 2) + jj] = oc[ii][jj];
}

// ---------------- residual depthwise conv along seq, o += conv(v) ----------------
__global__ __launch_bounds__(256) void k_conv(const float* __restrict__ vg,
    const float* __restrict__ cw, float* __restrict__ o) {
  const int t = threadIdx.x;
  const int d = t & 63, nn = t >> 6;
  const int h = blockIdx.y;
  const int n = blockIdx.x * 4 + nn;
  const float* wp = cw + h * 33;
  float s = 0.f;
  #pragma unroll
  for (int j = 0; j < 33; ++j) {
    const int src = n + j - 16;
    if (src >= 0 && src < 16384)
      s += wp[j] * vg[((size_t)h * 16384 + src) * 64 + d];
  }
  o[(size_t)n * 512 + h * 64 + d] += s;
}

// ---------------- out = o @ w_out^T + b_out + x ----------------
__global__ __launch_bounds__(256) void k_out(const float* __restrict__ A,
    const float* __restrict__ B, const float* __restrict__ bias,
    const float* __restrict__ xres, float* __restrict__ out) {
  __shared__ float As[16][68];
  __shared__ float Bs[16][68];
  const int t = threadIdx.x, tx = t & 15, ty = t >> 4;
  const int bn = blockIdx.x, bm = blockIdx.y;
  const int lr = t >> 2, lk = (t & 3) << 2;
  const float* Ap = A + (size_t)(bm * 64 + lr) * 512 + lk;
  const float* Bp = B + (size_t)(bn * 64 + lr) * 512 + lk;
  float acc[4][4] = {{0.f}};
  for (int k0 = 0; k0 < 512; k0 += 16) {
    const float4 a4 = *(const float4*)(Ap + k0);
    const float4 b4 = *(const float4*)(Bp + k0);
    __syncthreads();
    As[lk+0][lr] = a4.x; As[lk+1][lr] = a4.y; As[lk+2][lr] = a4.z; As[lk+3][lr] = a4.w;
    Bs[lk+0][lr] = b4.x; Bs[lk+1][lr] = b4.y; Bs[lk+2][lr] = b4.z; Bs[lk+3][lr] = b4.w;
    __syncthreads();
    #pragma unroll
    for (int kq = 0; kq < 16; ++kq) {
      const float4 av = *(const float4*)&As[kq][ty << 2];
      const float4 bv = *(const float4*)&Bs[kq][tx << 2];
      FMA16(acc, av, bv);
    }
  }
  #pragma unroll
  for (int ii = 0; ii < 4; ++ii)
    #pragma unroll
    for (int jj = 0; jj < 4; ++jj) {
      const int i = bm * 64 + (ty << 2) + ii;
      const int j = bn * 64 + (tx << 2) + jj;
      out[(size_t)i * 512 + j] = acc[ii][jj] + bias[j] + xres[(size_t)i * 512 + j];
    }
}

extern "C" void kernel_launch(void* const* d_in, const int* in_sizes, int n_in,
                              void* d_out, int out_size, void* d_ws, size_t ws_size,
                              hipStream_t stream) {
  const float* x      = (const float*)d_in[0];
  const float* norm_w = (const float*)d_in[1];
  const float* norm_b = (const float*)d_in[2];
  const float* w_qkv  = (const float*)d_in[3];
  const float* w_out  = (const float*)d_in[4];
  const float* b_out  = (const float*)d_in[5];
  const float* conv_w = (const float*)d_in[6];
  float* out = (float*)d_out;
  float* ws  = (float*)d_ws;

  const size_t SZ_BIG = (size_t)16384 * 512;   // 8388608
  const size_t SZ_LM  = (size_t)8 * 256 * 64;  // 131072
  const size_t SZ_SQ  = (size_t)8 * 256 * 256; // 524288

  float* h    = ws;
  float* q    = h + SZ_BIG;
  float* k    = q + SZ_BIG;
  float* v    = k + SZ_BIG;
  float* ql   = v + SZ_BIG;
  float* kl   = ql + SZ_LM;
  float* a2   = kl + SZ_LM;
  float* z0   = a2 + SZ_SQ;
  float* z1   = z0 + SZ_SQ;
  float* P    = z1 + SZ_SQ;
  float* Q1   = P + SZ_SQ;
  float* Q2   = Q1 + SZ_SQ;
  float* W    = Q2 + SZ_SQ;
  float* lsum = W + SZ_LM;
  float* D    = lsum + 2048;
  float* cm   = D + SZ_LM;
  float* o    = cm + 64;
  // total ~45.6M floats (~174 MB)

  hipMemsetAsync(W, 0, (SZ_LM + 2048) * sizeof(float), stream);
  k_ln<<<16384, 128, 0, stream>>>(x, norm_w, norm_b, h);
  k_qkv<<<dim3(24, 256), 256, 0, stream>>>(h, w_qkv, q, k, v);
  k_landmark<<<dim3(256, 8, 2), 64, 0, stream>>>(q, k, ql, kl);
  k_attn2<<<dim3(256, 8), 256, 0, stream>>>(ql, kl, a2);
  k_colsum<<<8, 256, 0, stream>>>(a2, cm);
  k_z0<<<dim3(256, 8), 256, 0, stream>>>(a2, cm, z0);

  float* za = z0; float* zb = z1;
  for (int it = 0; it < 6; ++it) {
    k_gemm256<<<dim3(4, 4, 8), 256, 0, stream>>>(a2, za, P, 256, 256, 256,
        65536ULL, 65536ULL, 65536ULL, 1.f, 0.f, 0, nullptr, 0ULL);
    k_gemm256<<<dim3(4, 4, 8), 256, 0, stream>>>(P, P, Q1, 256, 256, 256,
        65536ULL, 65536ULL, 65536ULL, 1.f, 7.f, 1, nullptr, 0ULL);
    k_gemm256<<<dim3(4, 4, 8), 256, 0, stream>>>(P, Q1, Q2, 256, 256, 256,
        65536ULL, 65536ULL, 65536ULL, 1.f, 15.f, 1, nullptr, 0ULL);
    k_gemm256<<<dim3(4, 4, 8), 256, 0, stream>>>(za, Q2, zb, 256, 256, 256,
        65536ULL, 65536ULL, 65536ULL, 0.25f, 13.f, 1, nullptr, 0ULL);
    float* tmp = za; za = zb; zb = tmp;
  }

  k_w3<<<dim3(16, 4, 8), 256, 0, stream>>>(ql, k, v, W, lsum);
  k_gemm256<<<dim3(1, 4, 8), 256, 0, stream>>>(za, W, D, 256, 64, 64,
      65536ULL, 16384ULL, 16384ULL, 1.f, 0.f, 0, lsum, 256ULL);
  k_attn1<<<dim3(256, 8), 256, 0, stream>>>(q, kl, D, o);
  k_conv<<<dim3(4096, 8), 256, 0, stream>>>(v, conv_w, o);
  k_out<<<dim3(8, 256), 256, 0, stream>>>(o, w_out, b_out, x, out);
}

// Round 2
// 909.327 us; speedup vs baseline: 1.8876x; 1.8876x over previous
//
#include <hip/hip_runtime.h>
#include <hip/hip_bf16.h>

// Nystrom TransLayer, MI355X. Round 2: bf16 MFMA for qkv/out/w3/attn1; pinv chain stays fp32.
// B=1, N=16384, DIM=512, H=8, DH=64, M=256, pinv iters=6, conv k=33.

typedef __attribute__((ext_vector_type(8))) short bf16x8;
typedef __attribute__((ext_vector_type(4))) float f32x4;

#define MFMA16(A, B, C) __builtin_amdgcn_mfma_f32_16x16x32_bf16(A, B, C, 0, 0, 0)
#define GLD16(g, l) __builtin_amdgcn_global_load_lds( \
    (const __attribute__((address_space(1))) void*)(g), \
    (__attribute__((address_space(3))) void*)(l), 16, 0, 0)

static __device__ __forceinline__ unsigned short f2b(float f) {
  __hip_bfloat16 h = __float2bfloat16(f);
  return *reinterpret_cast<unsigned short*>(&h);
}
static __device__ __forceinline__ float b2f(unsigned short u) {
  return __uint_as_float(((unsigned)u) << 16);
}

#define FMA16(ACC, AV, BV) do { \
  ACC[0][0] += AV.x*BV.x; ACC[0][1] += AV.x*BV.y; ACC[0][2] += AV.x*BV.z; ACC[0][3] += AV.x*BV.w; \
  ACC[1][0] += AV.y*BV.x; ACC[1][1] += AV.y*BV.y; ACC[1][2] += AV.y*BV.z; ACC[1][3] += AV.y*BV.w; \
  ACC[2][0] += AV.z*BV.x; ACC[2][1] += AV.z*BV.y; ACC[2][2] += AV.z*BV.z; ACC[2][3] += AV.z*BV.w; \
  ACC[3][0] += AV.w*BV.x; ACC[3][1] += AV.w*BV.y; ACC[3][2] += AV.w*BV.z; ACC[3][3] += AV.w*BV.w; \
} while (0)

// ---------------- LayerNorm: x[16384,512] fp32 -> h bf16 ----------------
__global__ __launch_bounds__(128) void k_ln(const float* __restrict__ x,
    const float* __restrict__ w, const float* __restrict__ b, unsigned short* __restrict__ h) {
  const int row = blockIdx.x;
  const int t = threadIdx.x;
  const float4 xv = ((const float4*)(x + (size_t)row * 512))[t];
  float s  = xv.x + xv.y + xv.z + xv.w;
  float sq = xv.x*xv.x + xv.y*xv.y + xv.z*xv.z + xv.w*xv.w;
  #pragma unroll
  for (int o = 32; o > 0; o >>= 1) {
    s  += __shfl_down(s, o, 64);
    sq += __shfl_down(sq, o, 64);
  }
  __shared__ float ls[2], lq[2];
  if ((t & 63) == 0) { ls[t >> 6] = s; lq[t >> 6] = sq; }
  __syncthreads();
  s = ls[0] + ls[1]; sq = lq[0] + lq[1];
  const float mean = s * (1.0f / 512.0f);
  const float var  = sq * (1.0f / 512.0f) - mean * mean;
  const float rstd = rsqrtf(var + 1e-5f);
  const float4 wv = ((const float4*)w)[t];
  const float4 bv = ((const float4*)b)[t];
  ushort4 hv;
  hv.x = f2b((xv.x - mean) * rstd * wv.x + bv.x);
  hv.y = f2b((xv.y - mean) * rstd * wv.y + bv.y);
  hv.z = f2b((xv.z - mean) * rstd * wv.z + bv.z);
  hv.w = f2b((xv.w - mean) * rstd * wv.w + bv.w);
  ((ushort4*)(h + (size_t)row * 512))[t] = hv;
}

// ---------------- fp32 -> bf16 weight convert ----------------
__global__ __launch_bounds__(256) void k_cvt(const float* __restrict__ src,
    unsigned short* __restrict__ dst, int n4) {
  const int i = blockIdx.x * 256 + threadIdx.x;
  if (i < n4) {
    const float4 f = ((const float4*)src)[i];
    ushort4 u;
    u.x = f2b(f.x); u.y = f2b(f.y); u.z = f2b(f.z); u.w = f2b(f.w);
    ((ushort4*)dst)[i] = u;
  }
}

// ---------------- QKV MFMA: C[16384,1536] = h @ w_qkv^T, scatter q(f32+bf16), k(bf16), v(bf16) ----------------
__global__ __launch_bounds__(256) void k_qkv_mfma(const unsigned short* __restrict__ A,
    const unsigned short* __restrict__ B, float* __restrict__ qf,
    unsigned short* __restrict__ qb, unsigned short* __restrict__ kb,
    unsigned short* __restrict__ vb) {
  __shared__ unsigned short As[128 * 32];
  __shared__ unsigned short Bs[128 * 32];
  const int t = threadIdx.x;
  const int lane = t & 63, w = t >> 6;
  const int quad = lane >> 4, l15 = lane & 15;
  const int wm = (w >> 1) * 64, wn = (w & 1) * 64;
  const int m0 = blockIdx.y * 128, n0 = blockIdx.x * 128;
  f32x4 acc[4][4];
  #pragma unroll
  for (int i = 0; i < 4; ++i)
    #pragma unroll
    for (int j = 0; j < 4; ++j) acc[i][j] = (f32x4){0.f, 0.f, 0.f, 0.f};
  for (int k0 = 0; k0 < 512; k0 += 32) {
    __syncthreads();
    #pragma unroll
    for (int c = 0; c < 2; ++c) {
      const int slot = c * 256 + t;
      const int row = slot >> 2, seg = slot & 3;
      GLD16(A + (size_t)(m0 + row) * 512 + k0 + seg * 8, As + slot * 8);
      GLD16(B + (size_t)(n0 + row) * 512 + k0 + seg * 8, Bs + slot * 8);
    }
    __syncthreads();
    bf16x8 a[4], b[4];
    #pragma unroll
    for (int i = 0; i < 4; ++i)
      a[i] = *(const bf16x8*)(As + (wm + i * 16 + l15) * 32 + quad * 8);
    #pragma unroll
    for (int j = 0; j < 4; ++j)
      b[j] = *(const bf16x8*)(Bs + (wn + j * 16 + l15) * 32 + quad * 8);
    #pragma unroll
    for (int i = 0; i < 4; ++i)
      #pragma unroll
      for (int j = 0; j < 4; ++j)
        acc[i][j] = MFMA16(a[i], b[j], acc[i][j]);
  }
  const int part = n0 >> 9;  // 128-tile never crosses a 512 boundary
  #pragma unroll
  for (int i = 0; i < 4; ++i)
    #pragma unroll
    for (int j = 0; j < 4; ++j)
      #pragma unroll
      for (int r = 0; r < 4; ++r) {
        const int row = m0 + wm + i * 16 + quad * 4 + r;
        const int col = n0 + wn + j * 16 + l15;
        const int rem = col & 511;
        const int hd = rem >> 6, dd = rem & 63;
        const size_t idx = ((size_t)hd * 16384 + row) * 64 + dd;
        const float val = acc[i][j][r];
        if (part == 0)      { qf[idx] = val * 0.125f; qb[idx] = f2b(val * 0.125f); }
        else if (part == 1) kb[idx] = f2b(val);
        else                vb[idx] = f2b(val);
      }
}

// ---------------- v[h][n][d] -> vt[h][d][n] (bf16) ----------------
__global__ __launch_bounds__(256) void k_tr(const unsigned short* __restrict__ v,
    unsigned short* __restrict__ vt) {
  __shared__ unsigned short T[64][72];
  const int t = threadIdx.x;
  const int n0 = blockIdx.x * 64, h = blockIdx.y;
  const int n = t >> 2, sg = (t & 3) * 16;
  const unsigned short* p = v + ((size_t)(h * 16384 + n0 + n)) * 64 + sg;
  #pragma unroll
  for (int i = 0; i < 16; i += 4) {
    const ushort4 u = *(const ushort4*)(p + i);
    T[sg + i + 0][n] = u.x; T[sg + i + 1][n] = u.y;
    T[sg + i + 2][n] = u.z; T[sg + i + 3][n] = u.w;
  }
  __syncthreads();
  const int d = t >> 2, so = (t & 3) * 16;
  unsigned short* q = vt + ((size_t)(h * 64 + d)) * 16384 + n0 + so;
  #pragma unroll
  for (int i = 0; i < 16; i += 4) {
    ushort4 u;
    u.x = T[d][so + i]; u.y = T[d][so + i + 1];
    u.z = T[d][so + i + 2]; u.w = T[d][so + i + 3];
    *(ushort4*)(q + i) = u;
  }
}

// ---------------- landmarks (mean over 64 tokens): q fp32 path, k bf16 path ----------------
__global__ __launch_bounds__(64) void k_landmark(const float* __restrict__ qf,
    const unsigned short* __restrict__ kb, float* __restrict__ qlf,
    unsigned short* __restrict__ qlb, float* __restrict__ klf,
    unsigned short* __restrict__ klb) {
  const int d = threadIdx.x, m = blockIdx.x, h = blockIdx.y;
  const size_t oidx = ((size_t)h * 256 + m) * 64 + d;
  float s = 0.f;
  if (blockIdx.z == 0) {
    const float* p = qf + ((size_t)h * 16384 + m * 64) * 64 + d;
    #pragma unroll 8
    for (int t2 = 0; t2 < 64; ++t2) s += p[(size_t)t2 * 64];
    s *= (1.0f / 64.0f);
    qlf[oidx] = s; qlb[oidx] = f2b(s);
  } else {
    const unsigned short* p = kb + ((size_t)h * 16384 + m * 64) * 64 + d;
    #pragma unroll 8
    for (int t2 = 0; t2 < 64; ++t2) s += b2f(p[(size_t)t2 * 64]);
    s *= (1.0f / 64.0f);
    klf[oidx] = s; klb[oidx] = f2b(s);
  }
}

// ---------------- attn2 = softmax(q_l @ k_l^T) rows (fp32) ----------------
__global__ __launch_bounds__(256) void k_attn2(const float* __restrict__ ql,
    const float* __restrict__ kl, float* __restrict__ a2) {
  const int i = blockIdx.x, h = blockIdx.y, j = threadIdx.x;
  __shared__ float qrow[64];
  __shared__ float wred[4];
  __shared__ float wsum[4];
  if (j < 64) qrow[j] = ql[((size_t)h * 256 + i) * 64 + j];
  __syncthreads();
  const float* kr = kl + ((size_t)h * 256 + j) * 64;
  float s = 0.f;
  #pragma unroll 8
  for (int d = 0; d < 64; ++d) s += qrow[d] * kr[d];
  float mx = s;
  #pragma unroll
  for (int o2 = 32; o2 > 0; o2 >>= 1) mx = fmaxf(mx, __shfl_xor(mx, o2, 64));
  if ((j & 63) == 0) wred[j >> 6] = mx;
  __syncthreads();
  mx = fmaxf(fmaxf(wred[0], wred[1]), fmaxf(wred[2], wred[3]));
  const float e = __expf(s - mx);
  float sm = e;
  #pragma unroll
  for (int o2 = 32; o2 > 0; o2 >>= 1) sm += __shfl_xor(sm, o2, 64);
  if ((j & 63) == 0) wsum[j >> 6] = sm;
  __syncthreads();
  sm = wsum[0] + wsum[1] + wsum[2] + wsum[3];
  a2[((size_t)h * 256 + i) * 256 + j] = e / sm;
}

__global__ __launch_bounds__(256) void k_colsum(const float* __restrict__ a2,
    float* __restrict__ cm) {
  const int h = blockIdx.x, j = threadIdx.x;
  const float* p = a2 + (size_t)h * 65536 + j;
  float s = 0.f;
  for (int i = 0; i < 256; ++i) s += p[(size_t)i * 256];
  float mx = s;
  #pragma unroll
  for (int o2 = 32; o2 > 0; o2 >>= 1) mx = fmaxf(mx, __shfl_xor(mx, o2, 64));
  __shared__ float wred[4];
  if ((j & 63) == 0) wred[j >> 6] = mx;
  __syncthreads();
  if (j == 0) cm[h] = fmaxf(fmaxf(wred[0], wred[1]), fmaxf(wred[2], wred[3]));
}

__global__ __launch_bounds__(256) void k_z0(const float* __restrict__ a2,
    const float* __restrict__ cm, float* __restrict__ z) {
  const int i = blockIdx.x, h = blockIdx.y, j = threadIdx.x;
  float g = cm[0];
  #pragma unroll
  for (int c = 1; c < 8; ++c) g = fmaxf(g, cm[c]);
  z[((size_t)h * 256 + i) * 256 + j] = a2[((size_t)h * 256 + j) * 256 + i] / g;
}

// ---------------- fp32 batched 256-K GEMM (pinv chain + D) ----------------
__global__ __launch_bounds__(256) void k_gemm256(const float* __restrict__ A,
    const float* __restrict__ B, float* __restrict__ C,
    int lda, int ldb, int ldc,
    unsigned long long sA, unsigned long long sB, unsigned long long sC,
    float alpha, float sdiag, int use_diag,
    const float* __restrict__ rs, unsigned long long sRS) {
  A += (size_t)blockIdx.z * sA;
  B += (size_t)blockIdx.z * sB;
  C += (size_t)blockIdx.z * sC;
  if (rs) rs += (size_t)blockIdx.z * sRS;
  __shared__ float As[16][68];
  __shared__ float Bs[16][68];
  const int t = threadIdx.x, tx = t & 15, ty = t >> 4;
  const int bn = blockIdx.x, bm = blockIdx.y;
  const int lr = t >> 2, lk = (t & 3) << 2;
  const int bkr = t >> 4, bnc = (t & 15) << 2;
  float acc[4][4] = {{0.f}};
  for (int k0 = 0; k0 < 256; k0 += 16) {
    float4 a4 = *(const float4*)(A + (size_t)(bm * 64 + lr) * lda + k0 + lk);
    float4 b4 = *(const float4*)(B + (size_t)(k0 + bkr) * ldb + bn * 64 + bnc);
    if (use_diag) {
      const int kg = k0 + bkr, ngb = bn * 64 + bnc;
      b4.x = (kg == ngb + 0 ? sdiag : 0.f) - b4.x;
      b4.y = (kg == ngb + 1 ? sdiag : 0.f) - b4.y;
      b4.z = (kg == ngb + 2 ? sdiag : 0.f) - b4.z;
      b4.w = (kg == ngb + 3 ? sdiag : 0.f) - b4.w;
    }
    if (rs) {
      const float rv = 1.0f / rs[k0 + bkr];
      b4.x *= rv; b4.y *= rv; b4.z *= rv; b4.w *= rv;
    }
    __syncthreads();
    As[lk+0][lr] = a4.x; As[lk+1][lr] = a4.y; As[lk+2][lr] = a4.z; As[lk+3][lr] = a4.w;
    *(float4*)&Bs[bkr][bnc] = b4;
    __syncthreads();
    #pragma unroll
    for (int kq = 0; kq < 16; ++kq) {
      const float4 av = *(const float4*)&As[kq][ty << 2];
      const float4 bv = *(const float4*)&Bs[kq][tx << 2];
      FMA16(acc, av, bv);
    }
  }
  #pragma unroll
  for (int ii = 0; ii < 4; ++ii)
    #pragma unroll
    for (int jj = 0; jj < 4; ++jj)
      C[(size_t)(bm * 64 + (ty << 2) + ii) * ldc + bn * 64 + (tx << 2) + jj] =
          alpha * acc[ii][jj];
}

// ---------------- D[h][256][64] fp32 -> Dt[h][64][256] bf16 ----------------
__global__ __launch_bounds__(256) void k_trD(const float* __restrict__ D,
    unsigned short* __restrict__ dt) {
  __shared__ float T[64][65];
  const int t = threadIdx.x;
  const int mc = blockIdx.x, h = blockIdx.y;
  const int m = t >> 2, sg = (t & 3) * 16;
  const float* p = D + ((size_t)(h * 256 + mc * 64 + m)) * 64 + sg;
  #pragma unroll
  for (int i = 0; i < 16; i += 4) {
    const float4 f = *(const float4*)(p + i);
    T[sg + i + 0][m] = f.x; T[sg + i + 1][m] = f.y;
    T[sg + i + 2][m] = f.z; T[sg + i + 3][m] = f.w;
  }
  __syncthreads();
  const int d = t >> 2, so = (t & 3) * 16;
  unsigned short* q = dt + ((size_t)(h * 64 + d)) * 256 + mc * 64 + so;
  #pragma unroll
  for (int i = 0; i < 16; i += 4) {
    ushort4 u;
    u.x = f2b(T[d][so + i]);     u.y = f2b(T[d][so + i + 1]);
    u.z = f2b(T[d][so + i + 2]); u.w = f2b(T[d][so + i + 3]);
    *(ushort4*)(q + i) = u;
  }
}

// ---------------- fused attn3@v MFMA: W += exp(ql@k^T) @ v ; lsum += rowsum(exp) ----------------
__global__ __launch_bounds__(256) void k_w3_mfma(const unsigned short* __restrict__ qlb,
    const unsigned short* __restrict__ kb, const unsigned short* __restrict__ vt,
    float* __restrict__ W, float* __restrict__ lsum) {
  __shared__ unsigned short QLs[64 * 64];  // [m][d]
  __shared__ unsigned short Ks [64 * 64];  // [n][d]
  __shared__ unsigned short Vts[64 * 64];  // [d][n]
  __shared__ unsigned short Ps [64 * 64];  // [m][n]
  const int t = threadIdx.x;
  const int lane = t & 63, w = t >> 6;
  const int quad = lane >> 4, l15 = lane & 15;
  const int kc = blockIdx.x, mt = blockIdx.y, h = blockIdx.z;
  #pragma unroll
  for (int c = 0; c < 2; ++c) {
    const int slot = c * 256 + t;
    const int row = slot >> 3, seg = slot & 7;
    GLD16(qlb + ((size_t)(h * 256 + mt * 64 + row)) * 64 + seg * 8, QLs + slot * 8);
  }
  __syncthreads();
  const bf16x8 aq0 = *(const bf16x8*)(QLs + (w * 16 + l15) * 64 + quad * 8);
  const bf16x8 aq1 = *(const bf16x8*)(QLs + (w * 16 + l15) * 64 + quad * 8 + 32);
  f32x4 wacc[4];
  #pragma unroll
  for (int dt = 0; dt < 4; ++dt) wacc[dt] = (f32x4){0.f, 0.f, 0.f, 0.f};
  float lacc[4] = {0.f, 0.f, 0.f, 0.f};
  for (int ss = 0; ss < 16; ++ss) {
    const int n0 = kc * 1024 + ss * 64;
    __syncthreads();
    #pragma unroll
    for (int c = 0; c < 2; ++c) {
      const int slot = c * 256 + t;
      const int row = slot >> 3, seg = slot & 7;
      GLD16(kb + ((size_t)(h * 16384 + n0 + row)) * 64 + seg * 8, Ks + slot * 8);
      GLD16(vt + ((size_t)(h * 64 + row)) * 16384 + n0 + seg * 8, Vts + slot * 8);
    }
    __syncthreads();
    f32x4 s[4];
    #pragma unroll
    for (int j = 0; j < 4; ++j) {
      s[j] = (f32x4){0.f, 0.f, 0.f, 0.f};
      const bf16x8 b0 = *(const bf16x8*)(Ks + (j * 16 + l15) * 64 + quad * 8);
      const bf16x8 b1 = *(const bf16x8*)(Ks + (j * 16 + l15) * 64 + quad * 8 + 32);
      s[j] = MFMA16(aq0, b0, s[j]);
      s[j] = MFMA16(aq1, b1, s[j]);
    }
    #pragma unroll
    for (int j = 0; j < 4; ++j)
      #pragma unroll
      for (int r = 0; r < 4; ++r) {
        const float e = __expf(s[j][r]);
        lacc[r] += e;
        Ps[(w * 16 + quad * 4 + r) * 64 + j * 16 + l15] = f2b(e);
      }
    __syncthreads();
    const bf16x8 ap0 = *(const bf16x8*)(Ps + (w * 16 + l15) * 64 + quad * 8);
    const bf16x8 ap1 = *(const bf16x8*)(Ps + (w * 16 + l15) * 64 + quad * 8 + 32);
    #pragma unroll
    for (int dt = 0; dt < 4; ++dt) {
      const bf16x8 b0 = *(const bf16x8*)(Vts + (dt * 16 + l15) * 64 + quad * 8);
      const bf16x8 b1 = *(const bf16x8*)(Vts + (dt * 16 + l15) * 64 + quad * 8 + 32);
      wacc[dt] = MFMA16(ap0, b0, wacc[dt]);
      wacc[dt] = MFMA16(ap1, b1, wacc[dt]);
    }
  }
  #pragma unroll
  for (int dt = 0; dt < 4; ++dt)
    #pragma unroll
    for (int r = 0; r < 4; ++r)
      atomicAdd(&W[((size_t)(h * 256 + mt * 64 + w * 16 + quad * 4 + r)) * 64 + dt * 16 + l15],
                wacc[dt][r]);
  #pragma unroll
  for (int r = 0; r < 4; ++r) {
    #pragma unroll
    for (int msk = 1; msk < 16; msk <<= 1) lacc[r] += __shfl_xor(lacc[r], msk, 64);
    if (l15 == 0)
      atomicAdd(&lsum[h * 256 + mt * 64 + w * 16 + quad * 4 + r], lacc[r]);
  }
}

// ---------------- fused attn1@D MFMA: o = softmax(q@kl^T) @ D (bf16 out) ----------------
__global__ __launch_bounds__(256) void k_attn1_mfma(const unsigned short* __restrict__ qb,
    const unsigned short* __restrict__ klb, const unsigned short* __restrict__ dtb,
    unsigned short* __restrict__ o) {
  __shared__ unsigned short Qs[64 * 64];  // [tok][d]
  __shared__ unsigned short Ks[64 * 64];  // [m][d]
  __shared__ unsigned short Ds[64 * 64];  // [d][m]
  __shared__ unsigned short Ps[64 * 64];  // [tok][m]
  const int t = threadIdx.x;
  const int lane = t & 63, w = t >> 6;
  const int quad = lane >> 4, l15 = lane & 15;
  const int bt = blockIdx.x, h = blockIdx.y;
  const int n0 = bt * 64;
  #pragma unroll
  for (int c = 0; c < 2; ++c) {
    const int slot = c * 256 + t;
    const int row = slot >> 3, seg = slot & 7;
    GLD16(qb + ((size_t)(h * 16384 + n0 + row)) * 64 + seg * 8, Qs + slot * 8);
  }
  __syncthreads();
  const bf16x8 aq0 = *(const bf16x8*)(Qs + (w * 16 + l15) * 64 + quad * 8);
  const bf16x8 aq1 = *(const bf16x8*)(Qs + (w * 16 + l15) * 64 + quad * 8 + 32);
  f32x4 oacc[4];
  #pragma unroll
  for (int dt = 0; dt < 4; ++dt) oacc[dt] = (f32x4){0.f, 0.f, 0.f, 0.f};
  float lacc[4] = {0.f, 0.f, 0.f, 0.f};
  for (int mc = 0; mc < 4; ++mc) {
    const int m0 = mc * 64;
    __syncthreads();
    #pragma unroll
    for (int c = 0; c < 2; ++c) {
      const int slot = c * 256 + t;
      const int row = slot >> 3, seg = slot & 7;
      GLD16(klb + ((size_t)(h * 256 + m0 + row)) * 64 + seg * 8, Ks + slot * 8);
      GLD16(dtb + ((size_t)(h * 64 + row)) * 256 + m0 + seg * 8, Ds + slot * 8);
    }
    __syncthreads();
    f32x4 s[4];
    #pragma unroll
    for (int j = 0; j < 4; ++j) {
      s[j] = (f32x4){0.f, 0.f, 0.f, 0.f};
      const bf16x8 b0 = *(const bf16x8*)(Ks + (j * 16 + l15) * 64 + quad * 8);
      const bf16x8 b1 = *(const bf16x8*)(Ks + (j * 16 + l15) * 64 + quad * 8 + 32);
      s[j] = MFMA16(aq0, b0, s[j]);
      s[j] = MFMA16(aq1, b1, s[j]);
    }
    #pragma unroll
    for (int j = 0; j < 4; ++j)
      #pragma unroll
      for (int r = 0; r < 4; ++r) {
        const float e = __expf(s[j][r]);
        lacc[r] += e;
        Ps[(w * 16 + quad * 4 + r) * 64 + j * 16 + l15] = f2b(e);
      }
    __syncthreads();
    const bf16x8 ap0 = *(const bf16x8*)(Ps + (w * 16 + l15) * 64 + quad * 8);
    const bf16x8 ap1 = *(const bf16x8*)(Ps + (w * 16 + l15) * 64 + quad * 8 + 32);
    #pragma unroll
    for (int dt = 0; dt < 4; ++dt) {
      const bf16x8 b0 = *(const bf16x8*)(Ds + (dt * 16 + l15) * 64 + quad * 8);
      const bf16x8 b1 = *(const bf16x8*)(Ds + (dt * 16 + l15) * 64 + quad * 8 + 32);
      oacc[dt] = MFMA16(ap0, b0, oacc[dt]);
      oacc[dt] = MFMA16(ap1, b1, oacc[dt]);
    }
  }
  #pragma unroll
  for (int r = 0; r < 4; ++r)
    #pragma unroll
    for (int msk = 1; msk < 16; msk <<= 1) lacc[r] += __shfl_xor(lacc[r], msk, 64);
  #pragma unroll
  for (int dt = 0; dt < 4; ++dt)
    #pragma unroll
    for (int r = 0; r < 4; ++r) {
      const float val = oacc[dt][r] / lacc[r];
      o[((size_t)(n0 + w * 16 + quad * 4 + r)) * 512 + h * 64 + dt * 16 + l15] = f2b(val);
    }
}

// ---------------- residual depthwise conv: o += conv(v), bf16 ----------------
__global__ __launch_bounds__(256) void k_conv(const unsigned short* __restrict__ vb,
    const float* __restrict__ cw, unsigned short* __restrict__ o) {
  const int t = threadIdx.x;
  const int d = t & 63, nn = t >> 6;
  const int h = blockIdx.y;
  const int n = blockIdx.x * 4 + nn;
  const float* wp = cw + h * 33;
  float s = 0.f;
  #pragma unroll
  for (int j = 0; j < 33; ++j) {
    const int src = n + j - 16;
    if (src >= 0 && src < 16384)
      s += wp[j] * b2f(vb[((size_t)h * 16384 + src) * 64 + d]);
  }
  const size_t idx = (size_t)n * 512 + h * 64 + d;
  o[idx] = f2b(b2f(o[idx]) + s);
}

// ---------------- out MFMA: out = o @ w_out^T + b_out + x (fp32 out) ----------------
__global__ __launch_bounds__(256) void k_out_mfma(const unsigned short* __restrict__ A,
    const unsigned short* __restrict__ B, const float* __restrict__ bias,
    const float* __restrict__ xres, float* __restrict__ out) {
  __shared__ unsigned short As[128 * 32];
  __shared__ unsigned short Bs[128 * 32];
  const int t = threadIdx.x;
  const int lane = t & 63, w = t >> 6;
  const int quad = lane >> 4, l15 = lane & 15;
  const int wm = (w >> 1) * 64, wn = (w & 1) * 64;
  const int m0 = blockIdx.y * 128, n0 = blockIdx.x * 128;
  f32x4 acc[4][4];
  #pragma unroll
  for (int i = 0; i < 4; ++i)
    #pragma unroll
    for (int j = 0; j < 4; ++j) acc[i][j] = (f32x4){0.f, 0.f, 0.f, 0.f};
  for (int k0 = 0; k0 < 512; k0 += 32) {
    __syncthreads();
    #pragma unroll
    for (int c = 0; c < 2; ++c) {
      const int slot = c * 256 + t;
      const int row = slot >> 2, seg = slot & 3;
      GLD16(A + (size_t)(m0 + row) * 512 + k0 + seg * 8, As + slot * 8);
      GLD16(B + (size_t)(n0 + row) * 512 + k0 + seg * 8, Bs + slot * 8);
    }
    __syncthreads();
    bf16x8 a[4], b[4];
    #pragma unroll
    for (int i = 0; i < 4; ++i)
      a[i] = *(const bf16x8*)(As + (wm + i * 16 + l15) * 32 + quad * 8);
    #pragma unroll
    for (int j = 0; j < 4; ++j)
      b[j] = *(const bf16x8*)(Bs + (wn + j * 16 + l15) * 32 + quad * 8);
    #pragma unroll
    for (int i = 0; i < 4; ++i)
      #pragma unroll
      for (int j = 0; j < 4; ++j)
        acc[i][j] = MFMA16(a[i], b[j], acc[i][j]);
  }
  #pragma unroll
  for (int i = 0; i < 4; ++i)
    #pragma unroll
    for (int j = 0; j < 4; ++j)
      #pragma unroll
      for (int r = 0; r < 4; ++r) {
        const int row = m0 + wm + i * 16 + quad * 4 + r;
        const int col = n0 + wn + j * 16 + l15;
        out[(size_t)row * 512 + col] = acc[i][j][r] + bias[col] + xres[(size_t)row * 512 + col];
      }
}

extern "C" void kernel_launch(void* const* d_in, const int* in_sizes, int n_in,
                              void* d_out, int out_size, void* d_ws, size_t ws_size,
                              hipStream_t stream) {
  const float* x      = (const float*)d_in[0];
  const float* norm_w = (const float*)d_in[1];
  const float* norm_b = (const float*)d_in[2];
  const float* w_qkv  = (const float*)d_in[3];
  const float* w_out  = (const float*)d_in[4];
  const float* b_out  = (const float*)d_in[5];
  const float* conv_w = (const float*)d_in[6];
  float* out = (float*)d_out;

  char* cur = (char*)d_ws;
  auto alloc = [&](size_t bytes) -> char* {
    char* p = cur;
    cur += (bytes + 255) & ~(size_t)255;
    return p;
  };
  const size_t NB = (size_t)16384 * 512;  // big matrix elements
  const size_t LM = (size_t)8 * 256 * 64;
  const size_t SQ = (size_t)8 * 256 * 256;

  unsigned short* h_b  = (unsigned short*)alloc(NB * 2);
  unsigned short* wq_b = (unsigned short*)alloc((size_t)1536 * 512 * 2);
  unsigned short* wo_b = (unsigned short*)alloc((size_t)512 * 512 * 2);
  float*          qf   = (float*)alloc(NB * 4);
  unsigned short* qb   = (unsigned short*)alloc(NB * 2);
  unsigned short* kb   = (unsigned short*)alloc(NB * 2);
  unsigned short* vb   = (unsigned short*)alloc(NB * 2);
  unsigned short* vt   = (unsigned short*)alloc(NB * 2);
  float*          qlf  = (float*)alloc(LM * 4);
  float*          klf  = (float*)alloc(LM * 4);
  unsigned short* qlb  = (unsigned short*)alloc(LM * 2);
  unsigned short* klb  = (unsigned short*)alloc(LM * 2);
  float*          a2   = (float*)alloc(SQ * 4);
  float*          z0   = (float*)alloc(SQ * 4);
  float*          z1   = (float*)alloc(SQ * 4);
  float*          Pp   = (float*)alloc(SQ * 4);
  float*          Q1   = (float*)alloc(SQ * 4);
  float*          Q2   = (float*)alloc(SQ * 4);
  float*          W    = (float*)alloc(LM * 4 + 2048 * 4);  // W then lsum, contiguous
  float*          lsum = W + LM;
  float*          D    = (float*)alloc(LM * 4);
  unsigned short* dtb  = (unsigned short*)alloc(LM * 2);
  float*          cm   = (float*)alloc(64 * 4);
  unsigned short* o_b  = (unsigned short*)alloc(NB * 2);

  hipMemsetAsync(W, 0, (LM + 2048) * sizeof(float), stream);
  k_ln<<<16384, 128, 0, stream>>>(x, norm_w, norm_b, h_b);
  k_cvt<<<768, 256, 0, stream>>>(w_qkv, wq_b, 196608);
  k_cvt<<<256, 256, 0, stream>>>(w_out, wo_b, 65536);
  k_qkv_mfma<<<dim3(12, 128), 256, 0, stream>>>(h_b, wq_b, qf, qb, kb, vb);
  k_tr<<<dim3(256, 8), 256, 0, stream>>>(vb, vt);
  k_landmark<<<dim3(256, 8, 2), 64, 0, stream>>>(qf, kb, qlf, qlb, klf, klb);
  k_attn2<<<dim3(256, 8), 256, 0, stream>>>(qlf, klf, a2);
  k_colsum<<<8, 256, 0, stream>>>(a2, cm);
  k_z0<<<dim3(256, 8), 256, 0, stream>>>(a2, cm, z0);

  float* za = z0; float* zb = z1;
  for (int it = 0; it < 6; ++it) {
    k_gemm256<<<dim3(4, 4, 8), 256, 0, stream>>>(a2, za, Pp, 256, 256, 256,
        65536ULL, 65536ULL, 65536ULL, 1.f, 0.f, 0, nullptr, 0ULL);
    k_gemm256<<<dim3(4, 4, 8), 256, 0, stream>>>(Pp, Pp, Q1, 256, 256, 256,
        65536ULL, 65536ULL, 65536ULL, 1.f, 7.f, 1, nullptr, 0ULL);
    k_gemm256<<<dim3(4, 4, 8), 256, 0, stream>>>(Pp, Q1, Q2, 256, 256, 256,
        65536ULL, 65536ULL, 65536ULL, 1.f, 15.f, 1, nullptr, 0ULL);
    k_gemm256<<<dim3(4, 4, 8), 256, 0, stream>>>(za, Q2, zb, 256, 256, 256,
        65536ULL, 65536ULL, 65536ULL, 0.25f, 13.f, 1, nullptr, 0ULL);
    float* tmp = za; za = zb; zb = tmp;
  }

  k_w3_mfma<<<dim3(16, 4, 8), 256, 0, stream>>>(qlb, kb, vt, W, lsum);
  k_gemm256<<<dim3(1, 4, 8), 256, 0, stream>>>(za, W, D, 256, 64, 64,
      65536ULL, 16384ULL, 16384ULL, 1.f, 0.f, 0, lsum, 256ULL);
  k_trD<<<dim3(4, 8), 256, 0, stream>>>(D, dtb);
  k_attn1_mfma<<<dim3(256, 8), 256, 0, stream>>>(qb, klb, dtb, o_b);
  k_conv<<<dim3(4096, 8), 256, 0, stream>>>(vb, conv_w, o_b);
  k_out_mfma<<<dim3(4, 128), 256, 0, stream>>>(o_b, wo_b, b_out, x, out);
}

// Round 3
// 739.074 us; speedup vs baseline: 2.3225x; 1.2304x over previous
//
#include <hip/hip_runtime.h>
#include <hip/hip_bf16.h>

// Nystrom TransLayer, MI355X. Round 3: conv fused into attn1 epilogue; drop qf;
// faster landmark + z0 transpose. Pinv chain still fp32 (profile next).

typedef __attribute__((ext_vector_type(8))) short bf16x8;
typedef __attribute__((ext_vector_type(4))) float f32x4;

#define MFMA16(A, B, C) __builtin_amdgcn_mfma_f32_16x16x32_bf16(A, B, C, 0, 0, 0)
#define GLD16(g, l) __builtin_amdgcn_global_load_lds( \
    (const __attribute__((address_space(1))) void*)(g), \
    (__attribute__((address_space(3))) void*)(l), 16, 0, 0)

static __device__ __forceinline__ unsigned short f2b(float f) {
  __hip_bfloat16 h = __float2bfloat16(f);
  return *reinterpret_cast<unsigned short*>(&h);
}
static __device__ __forceinline__ float b2f(unsigned short u) {
  return __uint_as_float(((unsigned)u) << 16);
}

#define FMA16(ACC, AV, BV) do { \
  ACC[0][0] += AV.x*BV.x; ACC[0][1] += AV.x*BV.y; ACC[0][2] += AV.x*BV.z; ACC[0][3] += AV.x*BV.w; \
  ACC[1][0] += AV.y*BV.x; ACC[1][1] += AV.y*BV.y; ACC[1][2] += AV.y*BV.z; ACC[1][3] += AV.y*BV.w; \
  ACC[2][0] += AV.z*BV.x; ACC[2][1] += AV.z*BV.y; ACC[2][2] += AV.z*BV.z; ACC[2][3] += AV.z*BV.w; \
  ACC[3][0] += AV.w*BV.x; ACC[3][1] += AV.w*BV.y; ACC[3][2] += AV.w*BV.z; ACC[3][3] += AV.w*BV.w; \
} while (0)

// ---------------- LayerNorm: x[16384,512] fp32 -> h bf16 ----------------
__global__ __launch_bounds__(128) void k_ln(const float* __restrict__ x,
    const float* __restrict__ w, const float* __restrict__ b, unsigned short* __restrict__ h) {
  const int row = blockIdx.x;
  const int t = threadIdx.x;
  const float4 xv = ((const float4*)(x + (size_t)row * 512))[t];
  float s  = xv.x + xv.y + xv.z + xv.w;
  float sq = xv.x*xv.x + xv.y*xv.y + xv.z*xv.z + xv.w*xv.w;
  #pragma unroll
  for (int o = 32; o > 0; o >>= 1) {
    s  += __shfl_down(s, o, 64);
    sq += __shfl_down(sq, o, 64);
  }
  __shared__ float ls[2], lq[2];
  if ((t & 63) == 0) { ls[t >> 6] = s; lq[t >> 6] = sq; }
  __syncthreads();
  s = ls[0] + ls[1]; sq = lq[0] + lq[1];
  const float mean = s * (1.0f / 512.0f);
  const float var  = sq * (1.0f / 512.0f) - mean * mean;
  const float rstd = rsqrtf(var + 1e-5f);
  const float4 wv = ((const float4*)w)[t];
  const float4 bv = ((const float4*)b)[t];
  ushort4 hv;
  hv.x = f2b((xv.x - mean) * rstd * wv.x + bv.x);
  hv.y = f2b((xv.y - mean) * rstd * wv.y + bv.y);
  hv.z = f2b((xv.z - mean) * rstd * wv.z + bv.z);
  hv.w = f2b((xv.w - mean) * rstd * wv.w + bv.w);
  ((ushort4*)(h + (size_t)row * 512))[t] = hv;
}

// ---------------- fp32 -> bf16 weight convert ----------------
__global__ __launch_bounds__(256) void k_cvt(const float* __restrict__ src,
    unsigned short* __restrict__ dst, int n4) {
  const int i = blockIdx.x * 256 + threadIdx.x;
  if (i < n4) {
    const float4 f = ((const float4*)src)[i];
    ushort4 u;
    u.x = f2b(f.x); u.y = f2b(f.y); u.z = f2b(f.z); u.w = f2b(f.w);
    ((ushort4*)dst)[i] = u;
  }
}

// ---------------- QKV MFMA: C[16384,1536] = h @ w_qkv^T, scatter q,k,v (bf16) ----------------
__global__ __launch_bounds__(256) void k_qkv_mfma(const unsigned short* __restrict__ A,
    const unsigned short* __restrict__ B,
    unsigned short* __restrict__ qb, unsigned short* __restrict__ kb,
    unsigned short* __restrict__ vb) {
  __shared__ unsigned short As[128 * 32];
  __shared__ unsigned short Bs[128 * 32];
  const int t = threadIdx.x;
  const int lane = t & 63, w = t >> 6;
  const int quad = lane >> 4, l15 = lane & 15;
  const int wm = (w >> 1) * 64, wn = (w & 1) * 64;
  const int m0 = blockIdx.y * 128, n0 = blockIdx.x * 128;
  f32x4 acc[4][4];
  #pragma unroll
  for (int i = 0; i < 4; ++i)
    #pragma unroll
    for (int j = 0; j < 4; ++j) acc[i][j] = (f32x4){0.f, 0.f, 0.f, 0.f};
  for (int k0 = 0; k0 < 512; k0 += 32) {
    __syncthreads();
    #pragma unroll
    for (int c = 0; c < 2; ++c) {
      const int slot = c * 256 + t;
      const int row = slot >> 2, seg = slot & 3;
      GLD16(A + (size_t)(m0 + row) * 512 + k0 + seg * 8, As + slot * 8);
      GLD16(B + (size_t)(n0 + row) * 512 + k0 + seg * 8, Bs + slot * 8);
    }
    __syncthreads();
    bf16x8 a[4], b[4];
    #pragma unroll
    for (int i = 0; i < 4; ++i)
      a[i] = *(const bf16x8*)(As + (wm + i * 16 + l15) * 32 + quad * 8);
    #pragma unroll
    for (int j = 0; j < 4; ++j)
      b[j] = *(const bf16x8*)(Bs + (wn + j * 16 + l15) * 32 + quad * 8);
    #pragma unroll
    for (int i = 0; i < 4; ++i)
      #pragma unroll
      for (int j = 0; j < 4; ++j)
        acc[i][j] = MFMA16(a[i], b[j], acc[i][j]);
  }
  const int part = n0 >> 9;  // 128-tile never crosses a 512 boundary
  #pragma unroll
  for (int i = 0; i < 4; ++i)
    #pragma unroll
    for (int j = 0; j < 4; ++j)
      #pragma unroll
      for (int r = 0; r < 4; ++r) {
        const int row = m0 + wm + i * 16 + quad * 4 + r;
        const int col = n0 + wn + j * 16 + l15;
        const int rem = col & 511;
        const int hd = rem >> 6, dd = rem & 63;
        const size_t idx = ((size_t)hd * 16384 + row) * 64 + dd;
        const float val = acc[i][j][r];
        if (part == 0)      qb[idx] = f2b(val * 0.125f);
        else if (part == 1) kb[idx] = f2b(val);
        else                vb[idx] = f2b(val);
      }
}

// ---------------- v[h][n][d] -> vt[h][d][n] (bf16) ----------------
__global__ __launch_bounds__(256) void k_tr(const unsigned short* __restrict__ v,
    unsigned short* __restrict__ vt) {
  __shared__ unsigned short T[64][72];
  const int t = threadIdx.x;
  const int n0 = blockIdx.x * 64, h = blockIdx.y;
  const int n = t >> 2, sg = (t & 3) * 16;
  const unsigned short* p = v + ((size_t)(h * 16384 + n0 + n)) * 64 + sg;
  #pragma unroll
  for (int i = 0; i < 16; i += 4) {
    const ushort4 u = *(const ushort4*)(p + i);
    T[sg + i + 0][n] = u.x; T[sg + i + 1][n] = u.y;
    T[sg + i + 2][n] = u.z; T[sg + i + 3][n] = u.w;
  }
  __syncthreads();
  const int d = t >> 2, so = (t & 3) * 16;
  unsigned short* q = vt + ((size_t)(h * 64 + d)) * 16384 + n0 + so;
  #pragma unroll
  for (int i = 0; i < 16; i += 4) {
    ushort4 u;
    u.x = T[d][so + i]; u.y = T[d][so + i + 1];
    u.z = T[d][so + i + 2]; u.w = T[d][so + i + 3];
    *(ushort4*)(q + i) = u;
  }
}

// ---------------- landmarks: mean over 64 tokens (fp32 accumulate of bf16) ----------------
__global__ __launch_bounds__(256) void k_landmark(const unsigned short* __restrict__ qb,
    const unsigned short* __restrict__ kb, float* __restrict__ qlf,
    unsigned short* __restrict__ qlb, float* __restrict__ klf,
    unsigned short* __restrict__ klb) {
  const int t = threadIdx.x, d = t & 63, grp = t >> 6;
  const int m = blockIdx.x, h = blockIdx.y;
  const unsigned short* src = blockIdx.z ? kb : qb;
  const unsigned short* p = src + ((size_t)h * 16384 + m * 64 + grp * 16) * 64 + d;
  float s = 0.f;
  #pragma unroll
  for (int i = 0; i < 16; ++i) s += b2f(p[(size_t)i * 64]);
  __shared__ float red[4][64];
  red[grp][d] = s;
  __syncthreads();
  if (t < 64) {
    float v = (red[0][d] + red[1][d]) + (red[2][d] + red[3][d]);
    v *= (1.0f / 64.0f);
    const size_t oi = ((size_t)h * 256 + m) * 64 + d;
    if (blockIdx.z == 0) { qlf[oi] = v; qlb[oi] = f2b(v); }
    else                 { klf[oi] = v; klb[oi] = f2b(v); }
  }
}

// ---------------- attn2 = softmax(q_l @ k_l^T) rows (fp32) ----------------
__global__ __launch_bounds__(256) void k_attn2(const float* __restrict__ ql,
    const float* __restrict__ kl, float* __restrict__ a2) {
  const int i = blockIdx.x, h = blockIdx.y, j = threadIdx.x;
  __shared__ float qrow[64];
  __shared__ float wred[4];
  __shared__ float wsum[4];
  if (j < 64) qrow[j] = ql[((size_t)h * 256 + i) * 64 + j];
  __syncthreads();
  const float* kr = kl + ((size_t)h * 256 + j) * 64;
  float s = 0.f;
  #pragma unroll 8
  for (int d = 0; d < 64; ++d) s += qrow[d] * kr[d];
  float mx = s;
  #pragma unroll
  for (int o2 = 32; o2 > 0; o2 >>= 1) mx = fmaxf(mx, __shfl_xor(mx, o2, 64));
  if ((j & 63) == 0) wred[j >> 6] = mx;
  __syncthreads();
  mx = fmaxf(fmaxf(wred[0], wred[1]), fmaxf(wred[2], wred[3]));
  const float e = __expf(s - mx);
  float sm = e;
  #pragma unroll
  for (int o2 = 32; o2 > 0; o2 >>= 1) sm += __shfl_xor(sm, o2, 64);
  if ((j & 63) == 0) wsum[j >> 6] = sm;
  __syncthreads();
  sm = wsum[0] + wsum[1] + wsum[2] + wsum[3];
  a2[((size_t)h * 256 + i) * 256 + j] = e / sm;
}

__global__ __launch_bounds__(256) void k_colsum(const float* __restrict__ a2,
    float* __restrict__ cm) {
  const int h = blockIdx.x, j = threadIdx.x;
  const float* p = a2 + (size_t)h * 65536 + j;
  float s = 0.f;
  for (int i = 0; i < 256; ++i) s += p[(size_t)i * 256];
  float mx = s;
  #pragma unroll
  for (int o2 = 32; o2 > 0; o2 >>= 1) mx = fmaxf(mx, __shfl_xor(mx, o2, 64));
  __shared__ float wred[4];
  if ((j & 63) == 0) wred[j >> 6] = mx;
  __syncthreads();
  if (j == 0) cm[h] = fmaxf(fmaxf(wred[0], wred[1]), fmaxf(wred[2], wred[3]));
}

// ---------------- z0 = a2^T / g, tiled LDS transpose ----------------
__global__ __launch_bounds__(256) void k_z0(const float* __restrict__ a2,
    const float* __restrict__ cm, float* __restrict__ z) {
  __shared__ float T[64][65];
  const int bi = blockIdx.x, bj = blockIdx.y, h = blockIdx.z;
  const int t = threadIdx.x;
  const int r = t >> 2, cseg = (t & 3) * 16;
  const float* p = a2 + ((size_t)h * 256 + bj * 64 + r) * 256 + bi * 64 + cseg;
  #pragma unroll
  for (int i = 0; i < 16; i += 4) {
    const float4 f = *(const float4*)(p + i);
    T[cseg + i + 0][r] = f.x; T[cseg + i + 1][r] = f.y;
    T[cseg + i + 2][r] = f.z; T[cseg + i + 3][r] = f.w;
  }
  float g = cm[0];
  #pragma unroll
  for (int c = 1; c < 8; ++c) g = fmaxf(g, cm[c]);
  const float inv = 1.0f / g;
  __syncthreads();
  float* q = z + ((size_t)h * 256 + bi * 64 + r) * 256 + bj * 64 + cseg;
  #pragma unroll
  for (int i = 0; i < 16; i += 4) {
    float4 f;
    f.x = T[r][cseg + i] * inv;     f.y = T[r][cseg + i + 1] * inv;
    f.z = T[r][cseg + i + 2] * inv; f.w = T[r][cseg + i + 3] * inv;
    *(float4*)(q + i) = f;
  }
}

// ---------------- fp32 batched 256-K GEMM (pinv chain + D) ----------------
__global__ __launch_bounds__(256) void k_gemm256(const float* __restrict__ A,
    const float* __restrict__ B, float* __restrict__ C,
    int lda, int ldb, int ldc,
    unsigned long long sA, unsigned long long sB, unsigned long long sC,
    float alpha, float sdiag, int use_diag,
    const float* __restrict__ rs, unsigned long long sRS) {
  A += (size_t)blockIdx.z * sA;
  B += (size_t)blockIdx.z * sB;
  C += (size_t)blockIdx.z * sC;
  if (rs) rs += (size_t)blockIdx.z * sRS;
  __shared__ float As[16][68];
  __shared__ float Bs[16][68];
  const int t = threadIdx.x, tx = t & 15, ty = t >> 4;
  const int bn = blockIdx.x, bm = blockIdx.y;
  const int lr = t >> 2, lk = (t & 3) << 2;
  const int bkr = t >> 4, bnc = (t & 15) << 2;
  float acc[4][4] = {{0.f}};
  for (int k0 = 0; k0 < 256; k0 += 16) {
    float4 a4 = *(const float4*)(A + (size_t)(bm * 64 + lr) * lda + k0 + lk);
    float4 b4 = *(const float4*)(B + (size_t)(k0 + bkr) * ldb + bn * 64 + bnc);
    if (use_diag) {
      const int kg = k0 + bkr, ngb = bn * 64 + bnc;
      b4.x = (kg == ngb + 0 ? sdiag : 0.f) - b4.x;
      b4.y = (kg == ngb + 1 ? sdiag : 0.f) - b4.y;
      b4.z = (kg == ngb + 2 ? sdiag : 0.f) - b4.z;
      b4.w = (kg == ngb + 3 ? sdiag : 0.f) - b4.w;
    }
    if (rs) {
      const float rv = 1.0f / rs[k0 + bkr];
      b4.x *= rv; b4.y *= rv; b4.z *= rv; b4.w *= rv;
    }
    __syncthreads();
    As[lk+0][lr] = a4.x; As[lk+1][lr] = a4.y; As[lk+2][lr] = a4.z; As[lk+3][lr] = a4.w;
    *(float4*)&Bs[bkr][bnc] = b4;
    __syncthreads();
    #pragma unroll
    for (int kq = 0; kq < 16; ++kq) {
      const float4 av = *(const float4*)&As[kq][ty << 2];
      const float4 bv = *(const float4*)&Bs[kq][tx << 2];
      FMA16(acc, av, bv);
    }
  }
  #pragma unroll
  for (int ii = 0; ii < 4; ++ii)
    #pragma unroll
    for (int jj = 0; jj < 4; ++jj)
      C[(size_t)(bm * 64 + (ty << 2) + ii) * ldc + bn * 64 + (tx << 2) + jj] =
          alpha * acc[ii][jj];
}

// ---------------- D[h][256][64] fp32 -> Dt[h][64][256] bf16 ----------------
__global__ __launch_bounds__(256) void k_trD(const float* __restrict__ D,
    unsigned short* __restrict__ dt) {
  __shared__ float T[64][65];
  const int t = threadIdx.x;
  const int mc = blockIdx.x, h = blockIdx.y;
  const int m = t >> 2, sg = (t & 3) * 16;
  const float* p = D + ((size_t)(h * 256 + mc * 64 + m)) * 64 + sg;
  #pragma unroll
  for (int i = 0; i < 16; i += 4) {
    const float4 f = *(const float4*)(p + i);
    T[sg + i + 0][m] = f.x; T[sg + i + 1][m] = f.y;
    T[sg + i + 2][m] = f.z; T[sg + i + 3][m] = f.w;
  }
  __syncthreads();
  const int d = t >> 2, so = (t & 3) * 16;
  unsigned short* q = dt + ((size_t)(h * 64 + d)) * 256 + mc * 64 + so;
  #pragma unroll
  for (int i = 0; i < 16; i += 4) {
    ushort4 u;
    u.x = f2b(T[d][so + i]);     u.y = f2b(T[d][so + i + 1]);
    u.z = f2b(T[d][so + i + 2]); u.w = f2b(T[d][so + i + 3]);
    *(ushort4*)(q + i) = u;
  }
}

// ---------------- fused attn3@v MFMA: W += exp(ql@k^T) @ v ; lsum += rowsum(exp) ----------------
__global__ __launch_bounds__(256) void k_w3_mfma(const unsigned short* __restrict__ qlb,
    const unsigned short* __restrict__ kb, const unsigned short* __restrict__ vt,
    float* __restrict__ W, float* __restrict__ lsum) {
  __shared__ unsigned short QLs[64 * 64];  // [m][d]
  __shared__ unsigned short Ks [64 * 64];  // [n][d]
  __shared__ unsigned short Vts[64 * 64];  // [d][n]
  __shared__ unsigned short Ps [64 * 64];  // [m][n]
  const int t = threadIdx.x;
  const int lane = t & 63, w = t >> 6;
  const int quad = lane >> 4, l15 = lane & 15;
  const int kc = blockIdx.x, mt = blockIdx.y, h = blockIdx.z;
  #pragma unroll
  for (int c = 0; c < 2; ++c) {
    const int slot = c * 256 + t;
    const int row = slot >> 3, seg = slot & 7;
    GLD16(qlb + ((size_t)(h * 256 + mt * 64 + row)) * 64 + seg * 8, QLs + slot * 8);
  }
  __syncthreads();
  const bf16x8 aq0 = *(const bf16x8*)(QLs + (w * 16 + l15) * 64 + quad * 8);
  const bf16x8 aq1 = *(const bf16x8*)(QLs + (w * 16 + l15) * 64 + quad * 8 + 32);
  f32x4 wacc[4];
  #pragma unroll
  for (int dt = 0; dt < 4; ++dt) wacc[dt] = (f32x4){0.f, 0.f, 0.f, 0.f};
  float lacc[4] = {0.f, 0.f, 0.f, 0.f};
  for (int ss = 0; ss < 16; ++ss) {
    const int n0 = kc * 1024 + ss * 64;
    __syncthreads();
    #pragma unroll
    for (int c = 0; c < 2; ++c) {
      const int slot = c * 256 + t;
      const int row = slot >> 3, seg = slot & 7;
      GLD16(kb + ((size_t)(h * 16384 + n0 + row)) * 64 + seg * 8, Ks + slot * 8);
      GLD16(vt + ((size_t)(h * 64 + row)) * 16384 + n0 + seg * 8, Vts + slot * 8);
    }
    __syncthreads();
    f32x4 s[4];
    #pragma unroll
    for (int j = 0; j < 4; ++j) {
      s[j] = (f32x4){0.f, 0.f, 0.f, 0.f};
      const bf16x8 b0 = *(const bf16x8*)(Ks + (j * 16 + l15) * 64 + quad * 8);
      const bf16x8 b1 = *(const bf16x8*)(Ks + (j * 16 + l15) * 64 + quad * 8 + 32);
      s[j] = MFMA16(aq0, b0, s[j]);
      s[j] = MFMA16(aq1, b1, s[j]);
    }
    #pragma unroll
    for (int j = 0; j < 4; ++j)
      #pragma unroll
      for (int r = 0; r < 4; ++r) {
        const float e = __expf(s[j][r]);
        lacc[r] += e;
        Ps[(w * 16 + quad * 4 + r) * 64 + j * 16 + l15] = f2b(e);
      }
    __syncthreads();
    const bf16x8 ap0 = *(const bf16x8*)(Ps + (w * 16 + l15) * 64 + quad * 8);
    const bf16x8 ap1 = *(const bf16x8*)(Ps + (w * 16 + l15) * 64 + quad * 8 + 32);
    #pragma unroll
    for (int dt = 0; dt < 4; ++dt) {
      const bf16x8 b0 = *(const bf16x8*)(Vts + (dt * 16 + l15) * 64 + quad * 8);
      const bf16x8 b1 = *(const bf16x8*)(Vts + (dt * 16 + l15) * 64 + quad * 8 + 32);
      wacc[dt] = MFMA16(ap0, b0, wacc[dt]);
      wacc[dt] = MFMA16(ap1, b1, wacc[dt]);
    }
  }
  #pragma unroll
  for (int dt = 0; dt < 4; ++dt)
    #pragma unroll
    for (int r = 0; r < 4; ++r)
      atomicAdd(&W[((size_t)(h * 256 + mt * 64 + w * 16 + quad * 4 + r)) * 64 + dt * 16 + l15],
                wacc[dt][r]);
  #pragma unroll
  for (int r = 0; r < 4; ++r) {
    #pragma unroll
    for (int msk = 1; msk < 16; msk <<= 1) lacc[r] += __shfl_xor(lacc[r], msk, 64);
    if (l15 == 0)
      atomicAdd(&lsum[h * 256 + mt * 64 + w * 16 + quad * 4 + r], lacc[r]);
  }
}

// ---------------- fused attn1@D + depthwise conv: o = softmax(q@kl^T)@D + conv(v) ----------------
__global__ __launch_bounds__(256) void k_attn1_mfma(const unsigned short* __restrict__ qb,
    const unsigned short* __restrict__ klb, const unsigned short* __restrict__ dtb,
    const unsigned short* __restrict__ vb, const float* __restrict__ cw,
    unsigned short* __restrict__ o) {
  __shared__ unsigned short Qs[64 * 64];  // [tok][d]
  __shared__ unsigned short Ks[64 * 64];  // [m][d]
  __shared__ unsigned short Ds[64 * 64];  // [d][m]
  __shared__ unsigned short Ps[64 * 64];  // [tok][m]
  __shared__ __align__(16) unsigned short Vc[96 * 64];  // v rows n0-16..n0+79
  __shared__ float Ws[33];
  const int t = threadIdx.x;
  const int lane = t & 63, w = t >> 6;
  const int quad = lane >> 4, l15 = lane & 15;
  const int bt = blockIdx.x, h = blockIdx.y;
  const int n0 = bt * 64;
  if (t < 33) Ws[t] = cw[h * 33 + t];
  // stage conv v tile (zero-padded at sequence edges)
  #pragma unroll
  for (int c = 0; c < 3; ++c) {
    const int slot = c * 256 + t;           // 768 slots of 8 ushorts
    const int row = slot >> 3, seg = slot & 7;
    const int g = n0 - 16 + row;
    uint4 u = {0u, 0u, 0u, 0u};
    if (g >= 0 && g < 16384)
      u = *(const uint4*)(vb + ((size_t)(h * 16384 + g)) * 64 + seg * 8);
    *(uint4*)(Vc + slot * 8) = u;
  }
  #pragma unroll
  for (int c = 0; c < 2; ++c) {
    const int slot = c * 256 + t;
    const int row = slot >> 3, seg = slot & 7;
    GLD16(qb + ((size_t)(h * 16384 + n0 + row)) * 64 + seg * 8, Qs + slot * 8);
  }
  __syncthreads();
  const bf16x8 aq0 = *(const bf16x8*)(Qs + (w * 16 + l15) * 64 + quad * 8);
  const bf16x8 aq1 = *(const bf16x8*)(Qs + (w * 16 + l15) * 64 + quad * 8 + 32);
  f32x4 oacc[4];
  #pragma unroll
  for (int dt = 0; dt < 4; ++dt) oacc[dt] = (f32x4){0.f, 0.f, 0.f, 0.f};
  float lacc[4] = {0.f, 0.f, 0.f, 0.f};
  for (int mc = 0; mc < 4; ++mc) {
    const int m0 = mc * 64;
    __syncthreads();
    #pragma unroll
    for (int c = 0; c < 2; ++c) {
      const int slot = c * 256 + t;
      const int row = slot >> 3, seg = slot & 7;
      GLD16(klb + ((size_t)(h * 256 + m0 + row)) * 64 + seg * 8, Ks + slot * 8);
      GLD16(dtb + ((size_t)(h * 64 + row)) * 256 + m0 + seg * 8, Ds + slot * 8);
    }
    __syncthreads();
    f32x4 s[4];
    #pragma unroll
    for (int j = 0; j < 4; ++j) {
      s[j] = (f32x4){0.f, 0.f, 0.f, 0.f};
      const bf16x8 b0 = *(const bf16x8*)(Ks + (j * 16 + l15) * 64 + quad * 8);
      const bf16x8 b1 = *(const bf16x8*)(Ks + (j * 16 + l15) * 64 + quad * 8 + 32);
      s[j] = MFMA16(aq0, b0, s[j]);
      s[j] = MFMA16(aq1, b1, s[j]);
    }
    #pragma unroll
    for (int j = 0; j < 4; ++j)
      #pragma unroll
      for (int r = 0; r < 4; ++r) {
        const float e = __expf(s[j][r]);
        lacc[r] += e;
        Ps[(w * 16 + quad * 4 + r) * 64 + j * 16 + l15] = f2b(e);
      }
    __syncthreads();
    const bf16x8 ap0 = *(const bf16x8*)(Ps + (w * 16 + l15) * 64 + quad * 8);
    const bf16x8 ap1 = *(const bf16x8*)(Ps + (w * 16 + l15) * 64 + quad * 8 + 32);
    #pragma unroll
    for (int dt = 0; dt < 4; ++dt) {
      const bf16x8 b0 = *(const bf16x8*)(Ds + (dt * 16 + l15) * 64 + quad * 8);
      const bf16x8 b1 = *(const bf16x8*)(Ds + (dt * 16 + l15) * 64 + quad * 8 + 32);
      oacc[dt] = MFMA16(ap0, b0, oacc[dt]);
      oacc[dt] = MFMA16(ap1, b1, oacc[dt]);
    }
  }
  #pragma unroll
  for (int r = 0; r < 4; ++r)
    #pragma unroll
    for (int msk = 1; msk < 16; msk <<= 1) lacc[r] += __shfl_xor(lacc[r], msk, 64);
  // epilogue: softmax-normalize + depthwise conv from Vc (sliding register window)
  const int rr0 = w * 16 + quad * 4;  // first of this lane's 4 token rows
  #pragma unroll
  for (int dt = 0; dt < 4; ++dt) {
    const int col = dt * 16 + l15;
    float vreg[36];
    #pragma unroll
    for (int i = 0; i < 36; ++i) vreg[i] = b2f(Vc[(rr0 + i) * 64 + col]);
    #pragma unroll
    for (int r = 0; r < 4; ++r) {
      float conv = 0.f;
      #pragma unroll
      for (int j = 0; j < 33; ++j) conv += Ws[j] * vreg[r + j];
      const float val = oacc[dt][r] / lacc[r] + conv;
      o[((size_t)(n0 + rr0 + r)) * 512 + h * 64 + col] = f2b(val);
    }
  }
}

// ---------------- out MFMA: out = o @ w_out^T + b_out + x (fp32 out) ----------------
__global__ __launch_bounds__(256) void k_out_mfma(const unsigned short* __restrict__ A,
    const unsigned short* __restrict__ B, const float* __restrict__ bias,
    const float* __restrict__ xres, float* __restrict__ out) {
  __shared__ unsigned short As[128 * 32];
  __shared__ unsigned short Bs[128 * 32];
  const int t = threadIdx.x;
  const int lane = t & 63, w = t >> 6;
  const int quad = lane >> 4, l15 = lane & 15;
  const int wm = (w >> 1) * 64, wn = (w & 1) * 64;
  const int m0 = blockIdx.y * 128, n0 = blockIdx.x * 128;
  f32x4 acc[4][4];
  #pragma unroll
  for (int i = 0; i < 4; ++i)
    #pragma unroll
    for (int j = 0; j < 4; ++j) acc[i][j] = (f32x4){0.f, 0.f, 0.f, 0.f};
  for (int k0 = 0; k0 < 512; k0 += 32) {
    __syncthreads();
    #pragma unroll
    for (int c = 0; c < 2; ++c) {
      const int slot = c * 256 + t;
      const int row = slot >> 2, seg = slot & 3;
      GLD16(A + (size_t)(m0 + row) * 512 + k0 + seg * 8, As + slot * 8);
      GLD16(B + (size_t)(n0 + row) * 512 + k0 + seg * 8, Bs + slot * 8);
    }
    __syncthreads();
    bf16x8 a[4], b[4];
    #pragma unroll
    for (int i = 0; i < 4; ++i)
      a[i] = *(const bf16x8*)(As + (wm + i * 16 + l15) * 32 + quad * 8);
    #pragma unroll
    for (int j = 0; j < 4; ++j)
      b[j] = *(const bf16x8*)(Bs + (wn + j * 16 + l15) * 32 + quad * 8);
    #pragma unroll
    for (int i = 0; i < 4; ++i)
      #pragma unroll
      for (int j = 0; j < 4; ++j)
        acc[i][j] = MFMA16(a[i], b[j], acc[i][j]);
  }
  #pragma unroll
  for (int i = 0; i < 4; ++i)
    #pragma unroll
    for (int j = 0; j < 4; ++j)
      #pragma unroll
      for (int r = 0; r < 4; ++r) {
        const int row = m0 + wm + i * 16 + quad * 4 + r;
        const int col = n0 + wn + j * 16 + l15;
        out[(size_t)row * 512 + col] = acc[i][j][r] + bias[col] + xres[(size_t)row * 512 + col];
      }
}

extern "C" void kernel_launch(void* const* d_in, const int* in_sizes, int n_in,
                              void* d_out, int out_size, void* d_ws, size_t ws_size,
                              hipStream_t stream) {
  const float* x      = (const float*)d_in[0];
  const float* norm_w = (const float*)d_in[1];
  const float* norm_b = (const float*)d_in[2];
  const float* w_qkv  = (const float*)d_in[3];
  const float* w_out  = (const float*)d_in[4];
  const float* b_out  = (const float*)d_in[5];
  const float* conv_w = (const float*)d_in[6];
  float* out = (float*)d_out;

  char* cur = (char*)d_ws;
  auto alloc = [&](size_t bytes) -> char* {
    char* p = cur;
    cur += (bytes + 255) & ~(size_t)255;
    return p;
  };
  const size_t NB = (size_t)16384 * 512;
  const size_t LM = (size_t)8 * 256 * 64;
  const size_t SQ = (size_t)8 * 256 * 256;

  unsigned short* h_b  = (unsigned short*)alloc(NB * 2);
  unsigned short* wq_b = (unsigned short*)alloc((size_t)1536 * 512 * 2);
  unsigned short* wo_b = (unsigned short*)alloc((size_t)512 * 512 * 2);
  unsigned short* qb   = (unsigned short*)alloc(NB * 2);
  unsigned short* kb   = (unsigned short*)alloc(NB * 2);
  unsigned short* vb   = (unsigned short*)alloc(NB * 2);
  unsigned short* vt   = (unsigned short*)alloc(NB * 2);
  float*          qlf  = (float*)alloc(LM * 4);
  float*          klf  = (float*)alloc(LM * 4);
  unsigned short* qlb  = (unsigned short*)alloc(LM * 2);
  unsigned short* klb  = (unsigned short*)alloc(LM * 2);
  float*          a2   = (float*)alloc(SQ * 4);
  float*          z0   = (float*)alloc(SQ * 4);
  float*          z1   = (float*)alloc(SQ * 4);
  float*          Pp   = (float*)alloc(SQ * 4);
  float*          Q1   = (float*)alloc(SQ * 4);
  float*          Q2   = (float*)alloc(SQ * 4);
  float*          W    = (float*)alloc(LM * 4 + 2048 * 4);
  float*          lsum = W + LM;
  float*          D    = (float*)alloc(LM * 4);
  unsigned short* dtb  = (unsigned short*)alloc(LM * 2);
  float*          cm   = (float*)alloc(64 * 4);
  unsigned short* o_b  = (unsigned short*)alloc(NB * 2);

  hipMemsetAsync(W, 0, (LM + 2048) * sizeof(float), stream);
  k_ln<<<16384, 128, 0, stream>>>(x, norm_w, norm_b, h_b);
  k_cvt<<<768, 256, 0, stream>>>(w_qkv, wq_b, 196608);
  k_cvt<<<256, 256, 0, stream>>>(w_out, wo_b, 65536);
  k_qkv_mfma<<<dim3(12, 128), 256, 0, stream>>>(h_b, wq_b, qb, kb, vb);
  k_tr<<<dim3(256, 8), 256, 0, stream>>>(vb, vt);
  k_landmark<<<dim3(256, 8, 2), 256, 0, stream>>>(qb, kb, qlf, qlb, klf, klb);
  k_attn2<<<dim3(256, 8), 256, 0, stream>>>(qlf, klf, a2);
  k_colsum<<<8, 256, 0, stream>>>(a2, cm);
  k_z0<<<dim3(4, 4, 8), 256, 0, stream>>>(a2, cm, z0);

  float* za = z0; float* zb = z1;
  for (int it = 0; it < 6; ++it) {
    k_gemm256<<<dim3(4, 4, 8), 256, 0, stream>>>(a2, za, Pp, 256, 256, 256,
        65536ULL, 65536ULL, 65536ULL, 1.f, 0.f, 0, nullptr, 0ULL);
    k_gemm256<<<dim3(4, 4, 8), 256, 0, stream>>>(Pp, Pp, Q1, 256, 256, 256,
        65536ULL, 65536ULL, 65536ULL, 1.f, 7.f, 1, nullptr, 0ULL);
    k_gemm256<<<dim3(4, 4, 8), 256, 0, stream>>>(Pp, Q1, Q2, 256, 256, 256,
        65536ULL, 65536ULL, 65536ULL, 1.f, 15.f, 1, nullptr, 0ULL);
    k_gemm256<<<dim3(4, 4, 8), 256, 0, stream>>>(za, Q2, zb, 256, 256, 256,
        65536ULL, 65536ULL, 65536ULL, 0.25f, 13.f, 1, nullptr, 0ULL);
    float* tmp = za; za = zb; zb = tmp;
  }

  k_w3_mfma<<<dim3(16, 4, 8), 256, 0, stream>>>(qlb, kb, vt, W, lsum);
  k_gemm256<<<dim3(1, 4, 8), 256, 0, stream>>>(za, W, D, 256, 64, 64,
      65536ULL, 16384ULL, 16384ULL, 1.f, 0.f, 0, lsum, 256ULL);
  k_trD<<<dim3(4, 8), 256, 0, stream>>>(D, dtb);
  k_attn1_mfma<<<dim3(256, 8), 256, 0, stream>>>(qb, klb, dtb, vb, conv_w, o_b);
  k_out_mfma<<<dim3(4, 128), 256, 0, stream>>>(o_b, wo_b, b_out, x, out);
}

// Round 4
// 450.310 us; speedup vs baseline: 3.8118x; 1.6413x over previous
//
#include <hip/hip_runtime.h>
#include <hip/hip_bf16.h>

// Nystrom TransLayer, MI355X. Round 4: bf16 MFMA pinv iters 1-5 (+fp32 iter-6 polish),
// conv-via-MFMA in attn1, XOR bank swizzle on 64-wide LDS buffers.

typedef __attribute__((ext_vector_type(8))) short bf16x8;
typedef __attribute__((ext_vector_type(4))) float f32x4;

#define MFMA16(A, B, C) __builtin_amdgcn_mfma_f32_16x16x32_bf16(A, B, C, 0, 0, 0)
#define GLD16(g, l) __builtin_amdgcn_global_load_lds( \
    (const __attribute__((address_space(1))) void*)(g), \
    (__attribute__((address_space(3))) void*)(l), 16, 0, 0)

static __device__ __forceinline__ unsigned short f2b(float f) {
  __hip_bfloat16 h = __float2bfloat16(f);
  return *reinterpret_cast<unsigned short*>(&h);
}
static __device__ __forceinline__ float b2f(unsigned short u) {
  return __uint_as_float(((unsigned)u) << 16);
}

#define FMA16(ACC, AV, BV) do { \
  ACC[0][0] += AV.x*BV.x; ACC[0][1] += AV.x*BV.y; ACC[0][2] += AV.x*BV.z; ACC[0][3] += AV.x*BV.w; \
  ACC[1][0] += AV.y*BV.x; ACC[1][1] += AV.y*BV.y; ACC[1][2] += AV.y*BV.z; ACC[1][3] += AV.y*BV.w; \
  ACC[2][0] += AV.z*BV.x; ACC[2][1] += AV.z*BV.y; ACC[2][2] += AV.z*BV.z; ACC[2][3] += AV.z*BV.w; \
  ACC[3][0] += AV.w*BV.x; ACC[3][1] += AV.w*BV.y; ACC[3][2] += AV.w*BV.z; ACC[3][3] += AV.w*BV.w; \
} while (0)

// ---------------- LayerNorm: x[16384,512] fp32 -> h bf16 ----------------
__global__ __launch_bounds__(128) void k_ln(const float* __restrict__ x,
    const float* __restrict__ w, const float* __restrict__ b, unsigned short* __restrict__ h) {
  const int row = blockIdx.x;
  const int t = threadIdx.x;
  const float4 xv = ((const float4*)(x + (size_t)row * 512))[t];
  float s  = xv.x + xv.y + xv.z + xv.w;
  float sq = xv.x*xv.x + xv.y*xv.y + xv.z*xv.z + xv.w*xv.w;
  #pragma unroll
  for (int o = 32; o > 0; o >>= 1) {
    s  += __shfl_down(s, o, 64);
    sq += __shfl_down(sq, o, 64);
  }
  __shared__ float ls[2], lq[2];
  if ((t & 63) == 0) { ls[t >> 6] = s; lq[t >> 6] = sq; }
  __syncthreads();
  s = ls[0] + ls[1]; sq = lq[0] + lq[1];
  const float mean = s * (1.0f / 512.0f);
  const float var  = sq * (1.0f / 512.0f) - mean * mean;
  const float rstd = rsqrtf(var + 1e-5f);
  const float4 wv = ((const float4*)w)[t];
  const float4 bv = ((const float4*)b)[t];
  ushort4 hv;
  hv.x = f2b((xv.x - mean) * rstd * wv.x + bv.x);
  hv.y = f2b((xv.y - mean) * rstd * wv.y + bv.y);
  hv.z = f2b((xv.z - mean) * rstd * wv.z + bv.z);
  hv.w = f2b((xv.w - mean) * rstd * wv.w + bv.w);
  ((ushort4*)(h + (size_t)row * 512))[t] = hv;
}

// ---------------- fp32 -> bf16 weight convert ----------------
__global__ __launch_bounds__(256) void k_cvt(const float* __restrict__ src,
    unsigned short* __restrict__ dst, int n4) {
  const int i = blockIdx.x * 256 + threadIdx.x;
  if (i < n4) {
    const float4 f = ((const float4*)src)[i];
    ushort4 u;
    u.x = f2b(f.x); u.y = f2b(f.y); u.z = f2b(f.z); u.w = f2b(f.w);
    ((ushort4*)dst)[i] = u;
  }
}

// ---------------- QKV MFMA: C[16384,1536] = h @ w_qkv^T, scatter q,k,v (bf16) ----------------
__global__ __launch_bounds__(256) void k_qkv_mfma(const unsigned short* __restrict__ A,
    const unsigned short* __restrict__ B,
    unsigned short* __restrict__ qb, unsigned short* __restrict__ kb,
    unsigned short* __restrict__ vb) {
  __shared__ unsigned short As[128 * 32];
  __shared__ unsigned short Bs[128 * 32];
  const int t = threadIdx.x;
  const int lane = t & 63, w = t >> 6;
  const int quad = lane >> 4, l15 = lane & 15;
  const int wm = (w >> 1) * 64, wn = (w & 1) * 64;
  const int m0 = blockIdx.y * 128, n0 = blockIdx.x * 128;
  f32x4 acc[4][4];
  #pragma unroll
  for (int i = 0; i < 4; ++i)
    #pragma unroll
    for (int j = 0; j < 4; ++j) acc[i][j] = (f32x4){0.f, 0.f, 0.f, 0.f};
  for (int k0 = 0; k0 < 512; k0 += 32) {
    __syncthreads();
    #pragma unroll
    for (int c = 0; c < 2; ++c) {
      const int slot = c * 256 + t;
      const int row = slot >> 2, seg = slot & 3;
      GLD16(A + (size_t)(m0 + row) * 512 + k0 + seg * 8, As + slot * 8);
      GLD16(B + (size_t)(n0 + row) * 512 + k0 + seg * 8, Bs + slot * 8);
    }
    __syncthreads();
    bf16x8 a[4], b[4];
    #pragma unroll
    for (int i = 0; i < 4; ++i)
      a[i] = *(const bf16x8*)(As + (wm + i * 16 + l15) * 32 + quad * 8);
    #pragma unroll
    for (int j = 0; j < 4; ++j)
      b[j] = *(const bf16x8*)(Bs + (wn + j * 16 + l15) * 32 + quad * 8);
    #pragma unroll
    for (int i = 0; i < 4; ++i)
      #pragma unroll
      for (int j = 0; j < 4; ++j)
        acc[i][j] = MFMA16(a[i], b[j], acc[i][j]);
  }
  const int part = n0 >> 9;
  #pragma unroll
  for (int i = 0; i < 4; ++i)
    #pragma unroll
    for (int j = 0; j < 4; ++j)
      #pragma unroll
      for (int r = 0; r < 4; ++r) {
        const int row = m0 + wm + i * 16 + quad * 4 + r;
        const int col = n0 + wn + j * 16 + l15;
        const int rem = col & 511;
        const int hd = rem >> 6, dd = rem & 63;
        const size_t idx = ((size_t)hd * 16384 + row) * 64 + dd;
        const float val = acc[i][j][r];
        if (part == 0)      qb[idx] = f2b(val * 0.125f);
        else if (part == 1) kb[idx] = f2b(val);
        else                vb[idx] = f2b(val);
      }
}

// ---------------- v[h][n][d] -> vt[h][d][n] (bf16) ----------------
__global__ __launch_bounds__(256) void k_tr(const unsigned short* __restrict__ v,
    unsigned short* __restrict__ vt) {
  __shared__ unsigned short T[64][72];
  const int t = threadIdx.x;
  const int n0 = blockIdx.x * 64, h = blockIdx.y;
  const int n = t >> 2, sg = (t & 3) * 16;
  const unsigned short* p = v + ((size_t)(h * 16384 + n0 + n)) * 64 + sg;
  #pragma unroll
  for (int i = 0; i < 16; i += 4) {
    const ushort4 u = *(const ushort4*)(p + i);
    T[sg + i + 0][n] = u.x; T[sg + i + 1][n] = u.y;
    T[sg + i + 2][n] = u.z; T[sg + i + 3][n] = u.w;
  }
  __syncthreads();
  const int d = t >> 2, so = (t & 3) * 16;
  unsigned short* q = vt + ((size_t)(h * 64 + d)) * 16384 + n0 + so;
  #pragma unroll
  for (int i = 0; i < 16; i += 4) {
    ushort4 u;
    u.x = T[d][so + i]; u.y = T[d][so + i + 1];
    u.z = T[d][so + i + 2]; u.w = T[d][so + i + 3];
    *(ushort4*)(q + i) = u;
  }
}

// ---------------- landmarks: mean over 64 tokens ----------------
__global__ __launch_bounds__(256) void k_landmark(const unsigned short* __restrict__ qb,
    const unsigned short* __restrict__ kb, float* __restrict__ qlf,
    unsigned short* __restrict__ qlb, float* __restrict__ klf,
    unsigned short* __restrict__ klb) {
  const int t = threadIdx.x, d = t & 63, grp = t >> 6;
  const int m = blockIdx.x, h = blockIdx.y;
  const unsigned short* src = blockIdx.z ? kb : qb;
  const unsigned short* p = src + ((size_t)h * 16384 + m * 64 + grp * 16) * 64 + d;
  float s = 0.f;
  #pragma unroll
  for (int i = 0; i < 16; ++i) s += b2f(p[(size_t)i * 64]);
  __shared__ float red[4][64];
  red[grp][d] = s;
  __syncthreads();
  if (t < 64) {
    float v = (red[0][d] + red[1][d]) + (red[2][d] + red[3][d]);
    v *= (1.0f / 64.0f);
    const size_t oi = ((size_t)h * 256 + m) * 64 + d;
    if (blockIdx.z == 0) { qlf[oi] = v; qlb[oi] = f2b(v); }
    else                 { klf[oi] = v; klb[oi] = f2b(v); }
  }
}

// ---------------- attn2 = softmax(q_l @ k_l^T) rows (fp32 + bf16 copy) ----------------
__global__ __launch_bounds__(256) void k_attn2(const float* __restrict__ ql,
    const float* __restrict__ kl, float* __restrict__ a2, unsigned short* __restrict__ a2b) {
  const int i = blockIdx.x, h = blockIdx.y, j = threadIdx.x;
  __shared__ float qrow[64];
  __shared__ float wred[4];
  __shared__ float wsum[4];
  if (j < 64) qrow[j] = ql[((size_t)h * 256 + i) * 64 + j];
  __syncthreads();
  const float* kr = kl + ((size_t)h * 256 + j) * 64;
  float s = 0.f;
  #pragma unroll 8
  for (int d = 0; d < 64; ++d) s += qrow[d] * kr[d];
  float mx = s;
  #pragma unroll
  for (int o2 = 32; o2 > 0; o2 >>= 1) mx = fmaxf(mx, __shfl_xor(mx, o2, 64));
  if ((j & 63) == 0) wred[j >> 6] = mx;
  __syncthreads();
  mx = fmaxf(fmaxf(wred[0], wred[1]), fmaxf(wred[2], wred[3]));
  const float e = __expf(s - mx);
  float sm = e;
  #pragma unroll
  for (int o2 = 32; o2 > 0; o2 >>= 1) sm += __shfl_xor(sm, o2, 64);
  if ((j & 63) == 0) wsum[j >> 6] = sm;
  __syncthreads();
  sm = wsum[0] + wsum[1] + wsum[2] + wsum[3];
  const float v = e / sm;
  const size_t idx = ((size_t)h * 256 + i) * 256 + j;
  a2[idx] = v;
  a2b[idx] = f2b(v);
}

__global__ __launch_bounds__(256) void k_colsum(const float* __restrict__ a2,
    float* __restrict__ cm) {
  const int h = blockIdx.x, j = threadIdx.x;
  const float* p = a2 + (size_t)h * 65536 + j;
  float s = 0.f;
  for (int i = 0; i < 256; ++i) s += p[(size_t)i * 256];
  float mx = s;
  #pragma unroll
  for (int o2 = 32; o2 > 0; o2 >>= 1) mx = fmaxf(mx, __shfl_xor(mx, o2, 64));
  __shared__ float wred[4];
  if ((j & 63) == 0) wred[j >> 6] = mx;
  __syncthreads();
  if (j == 0) cm[h] = fmaxf(fmaxf(wred[0], wred[1]), fmaxf(wred[2], wred[3]));
}

// ---------------- z0: z0b = (a2^T/g) bf16, z0t = (a2/g) bf16 ----------------
__global__ __launch_bounds__(256) void k_z0(const float* __restrict__ a2,
    const float* __restrict__ cm, unsigned short* __restrict__ z0b,
    unsigned short* __restrict__ z0t) {
  __shared__ float T[64][65];
  const int bi = blockIdx.x, bj = blockIdx.y, h = blockIdx.z;
  const int t = threadIdx.x;
  const int r = t >> 2, cseg = (t & 3) * 16;
  float g = cm[0];
  #pragma unroll
  for (int c = 1; c < 8; ++c) g = fmaxf(g, cm[c]);
  const float inv = 1.0f / g;
  const float* p = a2 + ((size_t)h * 256 + bj * 64 + r) * 256 + bi * 64 + cseg;
  unsigned short* qt = z0t + ((size_t)h * 256 + bj * 64 + r) * 256 + bi * 64 + cseg;
  #pragma unroll
  for (int i = 0; i < 16; i += 4) {
    const float4 f = *(const float4*)(p + i);
    T[cseg + i + 0][r] = f.x; T[cseg + i + 1][r] = f.y;
    T[cseg + i + 2][r] = f.z; T[cseg + i + 3][r] = f.w;
    ushort4 u;
    u.x = f2b(f.x * inv); u.y = f2b(f.y * inv);
    u.z = f2b(f.z * inv); u.w = f2b(f.w * inv);
    *(ushort4*)(qt + i) = u;
  }
  __syncthreads();
  unsigned short* qb_ = z0b + ((size_t)h * 256 + bi * 64 + r) * 256 + bj * 64 + cseg;
  #pragma unroll
  for (int i = 0; i < 16; i += 4) {
    ushort4 u;
    u.x = f2b(T[r][cseg + i] * inv);     u.y = f2b(T[r][cseg + i + 1] * inv);
    u.z = f2b(T[r][cseg + i + 2] * inv); u.w = f2b(T[r][cseg + i + 3] * inv);
    *(ushort4*)(qb_ + i) = u;
  }
}

// ---------------- bf16 MFMA batched 256^3 GEMM for pinv iters 1..5 ----------------
// C = alpha * A @ Bt^T  (Bt stored transposed [n][k]); writes:
//   Cn (nullable, bf16 [m][n]) = C
//   Ct (bf16 [n][m])           = use_diag ? sdiag*I - C^T : C^T
//   Cf (nullable, fp32 [m][n]) = C
__global__ __launch_bounds__(256) void k_pgemm(const unsigned short* __restrict__ A,
    const unsigned short* __restrict__ Bt, unsigned short* __restrict__ Cn,
    unsigned short* __restrict__ Ct, float* __restrict__ Cf,
    float alpha, float sdiag, int use_diag) {
  __shared__ unsigned short As[64 * 128];
  __shared__ unsigned short Bs[64 * 128];
  const int t = threadIdx.x;
  const int lane = t & 63, w = t >> 6;
  const int quad = lane >> 4, l15 = lane & 15;
  const int bn = blockIdx.x, bm = blockIdx.y, h = blockIdx.z;
  const size_t hs = (size_t)h * 65536;
  const unsigned short* Ap = A + hs + (size_t)(bm * 64) * 256;
  const unsigned short* Bp = Bt + hs + (size_t)(bn * 64) * 256;
  f32x4 acc[4];
  #pragma unroll
  for (int j = 0; j < 4; ++j) acc[j] = (f32x4){0.f, 0.f, 0.f, 0.f};
  for (int kh = 0; kh < 2; ++kh) {
    __syncthreads();
    #pragma unroll
    for (int c = 0; c < 4; ++c) {
      const int slot = c * 256 + t;            // 1024 slots: 64 rows x 16 chunks
      const int row = slot >> 4, pc = slot & 15;
      const int lc = pc ^ (row & 7);           // XOR bank swizzle on 16B chunks
      GLD16(Ap + (size_t)row * 256 + kh * 128 + lc * 8, As + slot * 8);
      GLD16(Bp + (size_t)row * 256 + kh * 128 + lc * 8, Bs + slot * 8);
    }
    __syncthreads();
    #pragma unroll
    for (int kc = 0; kc < 4; ++kc) {
      const int arow = w * 16 + l15;
      const bf16x8 a = *(const bf16x8*)(As + arow * 128 + ((kc * 4 + quad) ^ (arow & 7)) * 8);
      #pragma unroll
      for (int j = 0; j < 4; ++j) {
        const int brow = j * 16 + l15;
        const bf16x8 b = *(const bf16x8*)(Bs + brow * 128 + ((kc * 4 + quad) ^ (brow & 7)) * 8);
        acc[j] = MFMA16(a, b, acc[j]);
      }
    }
  }
  const int row0 = bm * 64 + w * 16 + quad * 4;
  #pragma unroll
  for (int j = 0; j < 4; ++j) {
    const int col = bn * 64 + j * 16 + l15;
    float v[4];
    #pragma unroll
    for (int r = 0; r < 4; ++r) v[r] = acc[j][r] * alpha;
    if (Cn) {
      #pragma unroll
      for (int r = 0; r < 4; ++r) Cn[hs + (size_t)(row0 + r) * 256 + col] = f2b(v[r]);
    }
    if (Cf) {
      #pragma unroll
      for (int r = 0; r < 4; ++r) Cf[hs + (size_t)(row0 + r) * 256 + col] = v[r];
    }
    ushort4 u;
    float tv[4];
    #pragma unroll
    for (int r = 0; r < 4; ++r)
      tv[r] = use_diag ? ((col == row0 + r ? sdiag : 0.f) - v[r]) : v[r];
    u.x = f2b(tv[0]); u.y = f2b(tv[1]); u.z = f2b(tv[2]); u.w = f2b(tv[3]);
    *(ushort4*)(Ct + hs + (size_t)col * 256 + row0) = u;
  }
}

// ---------------- fp32 batched 256-K GEMM (iter-6 polish + D) ----------------
__global__ __launch_bounds__(256) void k_gemm256(const float* __restrict__ A,
    const float* __restrict__ B, float* __restrict__ C,
    int lda, int ldb, int ldc,
    unsigned long long sA, unsigned long long sB, unsigned long long sC,
    float alpha, float sdiag, int use_diag,
    const float* __restrict__ rs, unsigned long long sRS) {
  A += (size_t)blockIdx.z * sA;
  B += (size_t)blockIdx.z * sB;
  C += (size_t)blockIdx.z * sC;
  if (rs) rs += (size_t)blockIdx.z * sRS;
  __shared__ float As[16][68];
  __shared__ float Bs[16][68];
  const int t = threadIdx.x, tx = t & 15, ty = t >> 4;
  const int bn = blockIdx.x, bm = blockIdx.y;
  const int lr = t >> 2, lk = (t & 3) << 2;
  const int bkr = t >> 4, bnc = (t & 15) << 2;
  float acc[4][4] = {{0.f}};
  for (int k0 = 0; k0 < 256; k0 += 16) {
    float4 a4 = *(const float4*)(A + (size_t)(bm * 64 + lr) * lda + k0 + lk);
    float4 b4 = *(const float4*)(B + (size_t)(k0 + bkr) * ldb + bn * 64 + bnc);
    if (use_diag) {
      const int kg = k0 + bkr, ngb = bn * 64 + bnc;
      b4.x = (kg == ngb + 0 ? sdiag : 0.f) - b4.x;
      b4.y = (kg == ngb + 1 ? sdiag : 0.f) - b4.y;
      b4.z = (kg == ngb + 2 ? sdiag : 0.f) - b4.z;
      b4.w = (kg == ngb + 3 ? sdiag : 0.f) - b4.w;
    }
    if (rs) {
      const float rv = 1.0f / rs[k0 + bkr];
      b4.x *= rv; b4.y *= rv; b4.z *= rv; b4.w *= rv;
    }
    __syncthreads();
    As[lk+0][lr] = a4.x; As[lk+1][lr] = a4.y; As[lk+2][lr] = a4.z; As[lk+3][lr] = a4.w;
    *(float4*)&Bs[bkr][bnc] = b4;
    __syncthreads();
    #pragma unroll
    for (int kq = 0; kq < 16; ++kq) {
      const float4 av = *(const float4*)&As[kq][ty << 2];
      const float4 bv = *(const float4*)&Bs[kq][tx << 2];
      FMA16(acc, av, bv);
    }
  }
  #pragma unroll
  for (int ii = 0; ii < 4; ++ii)
    #pragma unroll
    for (int jj = 0; jj < 4; ++jj)
      C[(size_t)(bm * 64 + (ty << 2) + ii) * ldc + bn * 64 + (tx << 2) + jj] =
          alpha * acc[ii][jj];
}

// ---------------- D[h][256][64] fp32 -> Dt[h][64][256] bf16 ----------------
__global__ __launch_bounds__(256) void k_trD(const float* __restrict__ D,
    unsigned short* __restrict__ dt) {
  __shared__ float T[64][65];
  const int t = threadIdx.x;
  const int mc = blockIdx.x, h = blockIdx.y;
  const int m = t >> 2, sg = (t & 3) * 16;
  const float* p = D + ((size_t)(h * 256 + mc * 64 + m)) * 64 + sg;
  #pragma unroll
  for (int i = 0; i < 16; i += 4) {
    const float4 f = *(const float4*)(p + i);
    T[sg + i + 0][m] = f.x; T[sg + i + 1][m] = f.y;
    T[sg + i + 2][m] = f.z; T[sg + i + 3][m] = f.w;
  }
  __syncthreads();
  const int d = t >> 2, so = (t & 3) * 16;
  unsigned short* q = dt + ((size_t)(h * 64 + d)) * 256 + mc * 64 + so;
  #pragma unroll
  for (int i = 0; i < 16; i += 4) {
    ushort4 u;
    u.x = f2b(T[d][so + i]);     u.y = f2b(T[d][so + i + 1]);
    u.z = f2b(T[d][so + i + 2]); u.w = f2b(T[d][so + i + 3]);
    *(ushort4*)(q + i) = u;
  }
}

// ---------------- fused attn3@v MFMA (swizzled LDS): W += exp(ql@k^T)@v ----------------
__global__ __launch_bounds__(256) void k_w3_mfma(const unsigned short* __restrict__ qlb,
    const unsigned short* __restrict__ kb, const unsigned short* __restrict__ vt,
    float* __restrict__ W, float* __restrict__ lsum) {
  __shared__ unsigned short QLs[64 * 64];
  __shared__ unsigned short Ks [64 * 64];
  __shared__ unsigned short Vts[64 * 64];
  __shared__ unsigned short Ps [64 * 64];
  const int t = threadIdx.x;
  const int lane = t & 63, w = t >> 6;
  const int quad = lane >> 4, l15 = lane & 15;
  const int kc = blockIdx.x, mt = blockIdx.y, h = blockIdx.z;
  #pragma unroll
  for (int c = 0; c < 2; ++c) {
    const int slot = c * 256 + t;
    const int row = slot >> 3, pc = slot & 7, lc = pc ^ (row & 7);
    GLD16(qlb + ((size_t)(h * 256 + mt * 64 + row)) * 64 + lc * 8, QLs + slot * 8);
  }
  __syncthreads();
  const int arow = w * 16 + l15;
  const bf16x8 aq0 = *(const bf16x8*)(QLs + arow * 64 + ((quad    ) ^ (arow & 7)) * 8);
  const bf16x8 aq1 = *(const bf16x8*)(QLs + arow * 64 + ((quad + 4) ^ (arow & 7)) * 8);
  f32x4 wacc[4];
  #pragma unroll
  for (int dt = 0; dt < 4; ++dt) wacc[dt] = (f32x4){0.f, 0.f, 0.f, 0.f};
  float lacc[4] = {0.f, 0.f, 0.f, 0.f};
  for (int ss = 0; ss < 16; ++ss) {
    const int n0 = kc * 1024 + ss * 64;
    __syncthreads();
    #pragma unroll
    for (int c = 0; c < 2; ++c) {
      const int slot = c * 256 + t;
      const int row = slot >> 3, pc = slot & 7, lc = pc ^ (row & 7);
      GLD16(kb + ((size_t)(h * 16384 + n0 + row)) * 64 + lc * 8, Ks + slot * 8);
      GLD16(vt + ((size_t)(h * 64 + row)) * 16384 + n0 + lc * 8, Vts + slot * 8);
    }
    __syncthreads();
    f32x4 s[4];
    #pragma unroll
    for (int j = 0; j < 4; ++j) {
      s[j] = (f32x4){0.f, 0.f, 0.f, 0.f};
      const int brow = j * 16 + l15;
      const bf16x8 b0 = *(const bf16x8*)(Ks + brow * 64 + ((quad    ) ^ (brow & 7)) * 8);
      const bf16x8 b1 = *(const bf16x8*)(Ks + brow * 64 + ((quad + 4) ^ (brow & 7)) * 8);
      s[j] = MFMA16(aq0, b0, s[j]);
      s[j] = MFMA16(aq1, b1, s[j]);
    }
    #pragma unroll
    for (int j = 0; j < 4; ++j)
      #pragma unroll
      for (int r = 0; r < 4; ++r) {
        const float e = __expf(s[j][r]);
        lacc[r] += e;
        const int prow = w * 16 + quad * 4 + r, pcol = j * 16 + l15;
        Ps[prow * 64 + (((pcol >> 3) ^ (prow & 7)) << 3) + (pcol & 7)] = f2b(e);
      }
    __syncthreads();
    const bf16x8 ap0 = *(const bf16x8*)(Ps + arow * 64 + ((quad    ) ^ (arow & 7)) * 8);
    const bf16x8 ap1 = *(const bf16x8*)(Ps + arow * 64 + ((quad + 4) ^ (arow & 7)) * 8);
    #pragma unroll
    for (int dt = 0; dt < 4; ++dt) {
      const int brow = dt * 16 + l15;
      const bf16x8 b0 = *(const bf16x8*)(Vts + brow * 64 + ((quad    ) ^ (brow & 7)) * 8);
      const bf16x8 b1 = *(const bf16x8*)(Vts + brow * 64 + ((quad + 4) ^ (brow & 7)) * 8);
      wacc[dt] = MFMA16(ap0, b0, wacc[dt]);
      wacc[dt] = MFMA16(ap1, b1, wacc[dt]);
    }
  }
  #pragma unroll
  for (int dt = 0; dt < 4; ++dt)
    #pragma unroll
    for (int r = 0; r < 4; ++r)
      atomicAdd(&W[((size_t)(h * 256 + mt * 64 + w * 16 + quad * 4 + r)) * 64 + dt * 16 + l15],
                wacc[dt][r]);
  #pragma unroll
  for (int r = 0; r < 4; ++r) {
    #pragma unroll
    for (int msk = 1; msk < 16; msk <<= 1) lacc[r] += __shfl_xor(lacc[r], msk, 64);
    if (l15 == 0)
      atomicAdd(&lsum[h * 256 + mt * 64 + w * 16 + quad * 4 + r], lacc[r]);
  }
}

// ---------------- fused attn1@D + conv-via-MFMA ----------------
__global__ __launch_bounds__(256) void k_attn1_mfma(const unsigned short* __restrict__ qb,
    const unsigned short* __restrict__ klb, const unsigned short* __restrict__ dtb,
    const unsigned short* __restrict__ vt, const float* __restrict__ cw,
    unsigned short* __restrict__ o) {
  __shared__ unsigned short Wb[64 * 96];   // first 8KB doubles as Q staging
  __shared__ unsigned short Ks[64 * 64];
  __shared__ unsigned short Ds[64 * 64];
  __shared__ unsigned short Ps[64 * 64];
  __shared__ float Wsm[33];
  const int t = threadIdx.x;
  const int lane = t & 63, w = t >> 6;
  const int quad = lane >> 4, l15 = lane & 15;
  const int bt = blockIdx.x, h = blockIdx.y;
  const int n0 = bt * 64;
  if (t < 33) Wsm[t] = cw[h * 33 + t];
  #pragma unroll
  for (int c = 0; c < 2; ++c) {
    const int slot = c * 256 + t;
    const int row = slot >> 3, pc = slot & 7, lc = pc ^ (row & 7);
    GLD16(qb + ((size_t)(h * 16384 + n0 + row)) * 64 + lc * 8, Wb + slot * 8);
  }
  __syncthreads();
  const int arow = w * 16 + l15;
  const bf16x8 aq0 = *(const bf16x8*)(Wb + arow * 64 + ((quad    ) ^ (arow & 7)) * 8);
  const bf16x8 aq1 = *(const bf16x8*)(Wb + arow * 64 + ((quad + 4) ^ (arow & 7)) * 8);
  __syncthreads();
  // build banded conv weight matrix Wb[n][g] (g in 0..95), XOR-swizzled (low 2 bits)
  {
    const int n = t >> 2;
    const int gb = (t & 3) * 24;
    #pragma unroll
    for (int i = 0; i < 24; ++i) {
      const int g = gb + i;
      const int j = g - n;
      const int src = n0 - 16 + g;
      const float val = (j >= 0 && j <= 32 && src >= 0 && src < 16384) ? Wsm[j] : 0.f;
      Wb[n * 96 + (((g >> 3) ^ (n & 3)) << 3) + (g & 7)] = f2b(val);
    }
  }
  __syncthreads();
  // conv: cacc[n_tok][d] = Wband @ vt^T, B-operand straight from global vt
  f32x4 cacc[4];
  #pragma unroll
  for (int dt = 0; dt < 4; ++dt) cacc[dt] = (f32x4){0.f, 0.f, 0.f, 0.f};
  #pragma unroll
  for (int kcc = 0; kcc < 3; ++kcc) {
    const bf16x8 a = *(const bf16x8*)(Wb + arow * 96 + (((kcc * 4 + quad) ^ (arow & 3)) << 3));
    int off = n0 - 16 + kcc * 32 + quad * 8;
    off = off < 0 ? 0 : (off > 16376 ? 16376 : off);
    #pragma unroll
    for (int dt = 0; dt < 4; ++dt) {
      const bf16x8 b = *(const bf16x8*)(vt + ((size_t)(h * 64 + dt * 16 + l15)) * 16384 + off);
      cacc[dt] = MFMA16(a, b, cacc[dt]);
    }
  }
  f32x4 oacc[4];
  #pragma unroll
  for (int dt = 0; dt < 4; ++dt) oacc[dt] = (f32x4){0.f, 0.f, 0.f, 0.f};
  float lacc[4] = {0.f, 0.f, 0.f, 0.f};
  for (int mc = 0; mc < 4; ++mc) {
    const int m0 = mc * 64;
    __syncthreads();
    #pragma unroll
    for (int c = 0; c < 2; ++c) {
      const int slot = c * 256 + t;
      const int row = slot >> 3, pc = slot & 7, lc = pc ^ (row & 7);
      GLD16(klb + ((size_t)(h * 256 + m0 + row)) * 64 + lc * 8, Ks + slot * 8);
      GLD16(dtb + ((size_t)(h * 64 + row)) * 256 + m0 + lc * 8, Ds + slot * 8);
    }
    __syncthreads();
    f32x4 s[4];
    #pragma unroll
    for (int j = 0; j < 4; ++j) {
      s[j] = (f32x4){0.f, 0.f, 0.f, 0.f};
      const int brow = j * 16 + l15;
      const bf16x8 b0 = *(const bf16x8*)(Ks + brow * 64 + ((quad    ) ^ (brow & 7)) * 8);
      const bf16x8 b1 = *(const bf16x8*)(Ks + brow * 64 + ((quad + 4) ^ (brow & 7)) * 8);
      s[j] = MFMA16(aq0, b0, s[j]);
      s[j] = MFMA16(aq1, b1, s[j]);
    }
    #pragma unroll
    for (int j = 0; j < 4; ++j)
      #pragma unroll
      for (int r = 0; r < 4; ++r) {
        const float e = __expf(s[j][r]);
        lacc[r] += e;
        const int prow = w * 16 + quad * 4 + r, pcol = j * 16 + l15;
        Ps[prow * 64 + (((pcol >> 3) ^ (prow & 7)) << 3) + (pcol & 7)] = f2b(e);
      }
    __syncthreads();
    const bf16x8 ap0 = *(const bf16x8*)(Ps + arow * 64 + ((quad    ) ^ (arow & 7)) * 8);
    const bf16x8 ap1 = *(const bf16x8*)(Ps + arow * 64 + ((quad + 4) ^ (arow & 7)) * 8);
    #pragma unroll
    for (int dt = 0; dt < 4; ++dt) {
      const int brow = dt * 16 + l15;
      const bf16x8 b0 = *(const bf16x8*)(Ds + brow * 64 + ((quad    ) ^ (brow & 7)) * 8);
      const bf16x8 b1 = *(const bf16x8*)(Ds + brow * 64 + ((quad + 4) ^ (brow & 7)) * 8);
      oacc[dt] = MFMA16(ap0, b0, oacc[dt]);
      oacc[dt] = MFMA16(ap1, b1, oacc[dt]);
    }
  }
  #pragma unroll
  for (int r = 0; r < 4; ++r)
    #pragma unroll
    for (int msk = 1; msk < 16; msk <<= 1) lacc[r] += __shfl_xor(lacc[r], msk, 64);
  #pragma unroll
  for (int dt = 0; dt < 4; ++dt)
    #pragma unroll
    for (int r = 0; r < 4; ++r) {
      const float val = oacc[dt][r] / lacc[r] + cacc[dt][r];
      o[((size_t)(n0 + w * 16 + quad * 4 + r)) * 512 + h * 64 + dt * 16 + l15] = f2b(val);
    }
}

// ---------------- out MFMA: out = o @ w_out^T + b_out + x (fp32 out) ----------------
__global__ __launch_bounds__(256) void k_out_mfma(const unsigned short* __restrict__ A,
    const unsigned short* __restrict__ B, const float* __restrict__ bias,
    const float* __restrict__ xres, float* __restrict__ out) {
  __shared__ unsigned short As[128 * 32];
  __shared__ unsigned short Bs[128 * 32];
  const int t = threadIdx.x;
  const int lane = t & 63, w = t >> 6;
  const int quad = lane >> 4, l15 = lane & 15;
  const int wm = (w >> 1) * 64, wn = (w & 1) * 64;
  const int m0 = blockIdx.y * 128, n0 = blockIdx.x * 128;
  f32x4 acc[4][4];
  #pragma unroll
  for (int i = 0; i < 4; ++i)
    #pragma unroll
    for (int j = 0; j < 4; ++j) acc[i][j] = (f32x4){0.f, 0.f, 0.f, 0.f};
  for (int k0 = 0; k0 < 512; k0 += 32) {
    __syncthreads();
    #pragma unroll
    for (int c = 0; c < 2; ++c) {
      const int slot = c * 256 + t;
      const int row = slot >> 2, seg = slot & 3;
      GLD16(A + (size_t)(m0 + row) * 512 + k0 + seg * 8, As + slot * 8);
      GLD16(B + (size_t)(n0 + row) * 512 + k0 + seg * 8, Bs + slot * 8);
    }
    __syncthreads();
    bf16x8 a[4], b[4];
    #pragma unroll
    for (int i = 0; i < 4; ++i)
      a[i] = *(const bf16x8*)(As + (wm + i * 16 + l15) * 32 + quad * 8);
    #pragma unroll
    for (int j = 0; j < 4; ++j)
      b[j] = *(const bf16x8*)(Bs + (wn + j * 16 + l15) * 32 + quad * 8);
    #pragma unroll
    for (int i = 0; i < 4; ++i)
      #pragma unroll
      for (int j = 0; j < 4; ++j)
        acc[i][j] = MFMA16(a[i], b[j], acc[i][j]);
  }
  #pragma unroll
  for (int i = 0; i < 4; ++i)
    #pragma unroll
    for (int j = 0; j < 4; ++j)
      #pragma unroll
      for (int r = 0; r < 4; ++r) {
        const int row = m0 + wm + i * 16 + quad * 4 + r;
        const int col = n0 + wn + j * 16 + l15;
        out[(size_t)row * 512 + col] = acc[i][j][r] + bias[col] + xres[(size_t)row * 512 + col];
      }
}

extern "C" void kernel_launch(void* const* d_in, const int* in_sizes, int n_in,
                              void* d_out, int out_size, void* d_ws, size_t ws_size,
                              hipStream_t stream) {
  const float* x      = (const float*)d_in[0];
  const float* norm_w = (const float*)d_in[1];
  const float* norm_b = (const float*)d_in[2];
  const float* w_qkv  = (const float*)d_in[3];
  const float* w_out  = (const float*)d_in[4];
  const float* b_out  = (const float*)d_in[5];
  const float* conv_w = (const float*)d_in[6];
  float* out = (float*)d_out;

  char* cur = (char*)d_ws;
  auto alloc = [&](size_t bytes) -> char* {
    char* p = cur;
    cur += (bytes + 255) & ~(size_t)255;
    return p;
  };
  const size_t NB = (size_t)16384 * 512;
  const size_t LM = (size_t)8 * 256 * 64;
  const size_t SQ = (size_t)8 * 256 * 256;

  unsigned short* h_b  = (unsigned short*)alloc(NB * 2);
  unsigned short* wq_b = (unsigned short*)alloc((size_t)1536 * 512 * 2);
  unsigned short* wo_b = (unsigned short*)alloc((size_t)512 * 512 * 2);
  unsigned short* qb   = (unsigned short*)alloc(NB * 2);
  unsigned short* kb   = (unsigned short*)alloc(NB * 2);
  unsigned short* vb   = (unsigned short*)alloc(NB * 2);
  unsigned short* vt   = (unsigned short*)alloc(NB * 2);
  float*          qlf  = (float*)alloc(LM * 4);
  float*          klf  = (float*)alloc(LM * 4);
  unsigned short* qlb  = (unsigned short*)alloc(LM * 2);
  unsigned short* klb  = (unsigned short*)alloc(LM * 2);
  float*          a2   = (float*)alloc(SQ * 4);
  unsigned short* a2b  = (unsigned short*)alloc(SQ * 2);
  unsigned short* z0b  = (unsigned short*)alloc(SQ * 2);
  unsigned short* z0t  = (unsigned short*)alloc(SQ * 2);
  unsigned short* Pn   = (unsigned short*)alloc(SQ * 2);
  unsigned short* Pt   = (unsigned short*)alloc(SQ * 2);
  unsigned short* Q1t  = (unsigned short*)alloc(SQ * 2);
  unsigned short* Q2t  = (unsigned short*)alloc(SQ * 2);
  unsigned short* zp0n = (unsigned short*)alloc(SQ * 2);
  unsigned short* zp0t = (unsigned short*)alloc(SQ * 2);
  unsigned short* zp1n = (unsigned short*)alloc(SQ * 2);
  unsigned short* zp1t = (unsigned short*)alloc(SQ * 2);
  float*          zf5  = (float*)alloc(SQ * 4);
  float*          zfin = (float*)alloc(SQ * 4);
  float*          Pp   = (float*)alloc(SQ * 4);
  float*          Q1   = (float*)alloc(SQ * 4);
  float*          Q2   = (float*)alloc(SQ * 4);
  float*          W    = (float*)alloc(LM * 4 + 2048 * 4);
  float*          lsum = W + LM;
  float*          D    = (float*)alloc(LM * 4);
  unsigned short* dtb  = (unsigned short*)alloc(LM * 2);
  float*          cm   = (float*)alloc(64 * 4);
  unsigned short* o_b  = (unsigned short*)alloc(NB * 2);

  hipMemsetAsync(W, 0, (LM + 2048) * sizeof(float), stream);
  k_ln<<<16384, 128, 0, stream>>>(x, norm_w, norm_b, h_b);
  k_cvt<<<768, 256, 0, stream>>>(w_qkv, wq_b, 196608);
  k_cvt<<<256, 256, 0, stream>>>(w_out, wo_b, 65536);
  k_qkv_mfma<<<dim3(12, 128), 256, 0, stream>>>(h_b, wq_b, qb, kb, vb);
  k_tr<<<dim3(256, 8), 256, 0, stream>>>(vb, vt);
  k_landmark<<<dim3(256, 8, 2), 256, 0, stream>>>(qb, kb, qlf, qlb, klf, klb);
  k_attn2<<<dim3(256, 8), 256, 0, stream>>>(qlf, klf, a2, a2b);
  k_colsum<<<8, 256, 0, stream>>>(a2, cm);
  k_z0<<<dim3(4, 4, 8), 256, 0, stream>>>(a2, cm, z0b, z0t);

  // pinv iterations 1..5 in bf16 MFMA (self-correcting; iter 6 polishes in fp32)
  unsigned short* zan = z0b; unsigned short* zat = z0t;
  for (int it = 0; it < 5; ++it) {
    unsigned short* zbn = (it & 1) ? zp1n : zp0n;
    unsigned short* zbt = (it & 1) ? zp1t : zp0t;
    k_pgemm<<<dim3(4, 4, 8), 256, 0, stream>>>(a2b, zat, Pn, Pt, nullptr, 1.f, 7.f, 1);
    k_pgemm<<<dim3(4, 4, 8), 256, 0, stream>>>(Pn, Pt, nullptr, Q1t, nullptr, 1.f, 15.f, 1);
    k_pgemm<<<dim3(4, 4, 8), 256, 0, stream>>>(Pn, Q1t, nullptr, Q2t, nullptr, 1.f, 13.f, 1);
    k_pgemm<<<dim3(4, 4, 8), 256, 0, stream>>>(zan, Q2t, zbn, zbt,
        it == 4 ? zf5 : nullptr, 0.25f, 0.f, 0);
    zan = zbn; zat = zbt;
  }
  // iter 6: fp32 polish
  k_gemm256<<<dim3(4, 4, 8), 256, 0, stream>>>(a2, zf5, Pp, 256, 256, 256,
      65536ULL, 65536ULL, 65536ULL, 1.f, 0.f, 0, nullptr, 0ULL);
  k_gemm256<<<dim3(4, 4, 8), 256, 0, stream>>>(Pp, Pp, Q1, 256, 256, 256,
      65536ULL, 65536ULL, 65536ULL, 1.f, 7.f, 1, nullptr, 0ULL);
  k_gemm256<<<dim3(4, 4, 8), 256, 0, stream>>>(Pp, Q1, Q2, 256, 256, 256,
      65536ULL, 65536ULL, 65536ULL, 1.f, 15.f, 1, nullptr, 0ULL);
  k_gemm256<<<dim3(4, 4, 8), 256, 0, stream>>>(zf5, Q2, zfin, 256, 256, 256,
      65536ULL, 65536ULL, 65536ULL, 0.25f, 13.f, 1, nullptr, 0ULL);

  k_w3_mfma<<<dim3(16, 4, 8), 256, 0, stream>>>(qlb, kb, vt, W, lsum);
  k_gemm256<<<dim3(1, 4, 8), 256, 0, stream>>>(zfin, W, D, 256, 64, 64,
      65536ULL, 16384ULL, 16384ULL, 1.f, 0.f, 0, lsum, 256ULL);
  k_trD<<<dim3(4, 8), 256, 0, stream>>>(D, dtb);
  k_attn1_mfma<<<dim3(256, 8), 256, 0, stream>>>(qb, klb, dtb, vt, conv_w, o_b);
  k_out_mfma<<<dim3(4, 128), 256, 0, stream>>>(o_b, wo_b, b_out, x, out);
}